// Round 4
// baseline (5588.169 us; speedup 1.0000x reference)
//
#include <hip/hip_runtime.h>
#include <cstddef>

#define NP 100000
#define NC 20000
#define NE 2000000
#define DIM 128
#define HID 128
#define OUTD 64

#define PBINS 1563        // ceil(NP/64)
#define CBINS 313         // ceil(NC/64)
#define PBINS_PAD 1568    // multiple of 32
#define CBINS_PAD 320

// ---------------- zero workspace region ----------------
__global__ void zero4_kernel(float4* p, size_t n4) {
    size_t i = blockIdx.x * (size_t)blockDim.x + threadIdx.x;
    size_t stride = (size_t)gridDim.x * blockDim.x;
    float4 z = make_float4(0.f, 0.f, 0.f, 0.f);
    for (; i < n4; i += stride) p[i] = z;
}

// ---------------- bin histogram ----------------
__global__ __launch_bounds__(256) void binhist_kernel(
    const int* __restrict__ ep, const int* __restrict__ ec,
    int* __restrict__ hbp, int* __restrict__ hbc)
{
    int e = blockIdx.x * 256 + threadIdx.x;
    if (e >= NE) return;
    atomicAdd(&hbp[ep[e] >> 6], 1);
    atomicAdd(&hbc[ec[e] >> 6], 1);
}

// ---------------- scan phase 1 ----------------
__global__ __launch_bounds__(256) void scan1_kernel(
    const int* __restrict__ in, int* __restrict__ out, int* __restrict__ bsums, int n)
{
    __shared__ int s[256];
    int t = threadIdx.x;
    int base = blockIdx.x * 1024 + t * 4;
    int4 v = make_int4(0, 0, 0, 0);
    if (base < n) v = *(const int4*)(in + base);
    int tsum = v.x + v.y + v.z + v.w;
    s[t] = tsum;
    __syncthreads();
    for (int off = 1; off < 256; off <<= 1) {
        int add = (t >= off) ? s[t - off] : 0;
        __syncthreads();
        s[t] += add;
        __syncthreads();
    }
    if (t == 255) bsums[blockIdx.x] = s[255];
    int tprefix = (t > 0) ? s[t - 1] : 0;
    if (base < n) {
        int4 o;
        o.x = tprefix;
        o.y = tprefix + v.x;
        o.z = tprefix + v.x + v.y;
        o.w = tprefix + v.x + v.y + v.z;
        *(int4*)(out + base) = o;
    }
}

// ---------------- scan phase 2 ----------------
__global__ __launch_bounds__(256) void scan2_kernel(int* __restrict__ bsums, int nb)
{
    __shared__ int s[256];
    int t = threadIdx.x;
    s[t] = (t < nb) ? bsums[t] : 0;
    __syncthreads();
    for (int off = 1; off < 256; off <<= 1) {
        int add = (t >= off) ? s[t - off] : 0;
        __syncthreads();
        s[t] += add;
        __syncthreads();
    }
    if (t < nb) bsums[t] = (t > 0) ? s[t - 1] : 0;
}

// ---------------- scan phase 3 ----------------
__global__ __launch_bounds__(256) void scan3_kernel(
    int* __restrict__ out, int* __restrict__ cur, const int* __restrict__ bsums,
    int n, int total)
{
    int t = threadIdx.x;
    int base = blockIdx.x * 1024 + t * 4;
    if (base < n) {
        int add = bsums[blockIdx.x];
        int4 v = *(const int4*)(out + base);
        v.x += add; v.y += add; v.z += add; v.w += add;
        *(int4*)(out + base) = v;
        *(int4*)(cur + base) = v;
    }
    if (blockIdx.x == 0 && t == 0) out[n] = total;
}

// ---------------- fill binned edge lists (packed key + weight) ----------------
// P-direction key: (p<<15)|c   (p<2^17, c<2^15)
// C-direction key: (c<<17)|p
__global__ __launch_bounds__(256) void binfill_kernel(
    const int* __restrict__ ep, const int* __restrict__ ec, const float* __restrict__ ew,
    int* __restrict__ curp, int* __restrict__ curc,
    uint2* __restrict__ bp, uint2* __restrict__ bc)
{
    int e = blockIdx.x * 256 + threadIdx.x;
    if (e >= NE) return;
    unsigned p = (unsigned)ep[e];
    unsigned c = (unsigned)ec[e];
    unsigned wb = __float_as_uint(ew[e]);
    int pos = atomicAdd(&curp[p >> 6], 1);
    bp[pos] = make_uint2((p << 15) | c, wb);
    int pos2 = atomicAdd(&curc[c >> 6], 1);
    bc[pos2] = make_uint2((c << 17) | p, wb);
}

// ---------------- binned aggregation: block per bin, LDS accumulator ----------------
template<int SHIFT, unsigned NMASK>
__global__ __launch_bounds__(256) void aggbin_kernel(
    const uint2* __restrict__ binned, const int* __restrict__ boff,
    const float* __restrict__ nbremb, float* __restrict__ msg, int nrows)
{
    __shared__ float ls[64 * DIM];   // 32 KB
    __shared__ float ldeg[64];
    int t = threadIdx.x;
    int wave = t >> 6;
    int lane = t & 63;

    #pragma unroll
    for (int i = 0; i < 32; ++i) ls[i * 256 + t] = 0.f;
    if (t < 64) ldeg[t] = 0.f;
    __syncthreads();

    int start = boff[blockIdx.x];
    int end   = boff[blockIdx.x + 1];
    for (int j = start + wave; j < end; j += 4) {
        uint2 v = binned[j];
        float w = __uint_as_float(v.y);
        int local = (int)((v.x >> SHIFT) & 63u);
        const float* nrow = nbremb + (size_t)(v.x & NMASK) * DIM;
        atomicAdd(&ls[local * DIM + lane],      w * nrow[lane]);
        atomicAdd(&ls[local * DIM + lane + 64], w * nrow[lane + 64]);
        if (lane == 0) atomicAdd(&ldeg[local], w);
    }
    __syncthreads();

    int rowbase = blockIdx.x * 64;
    for (int r = wave; r < 64; r += 4) {
        int row = rowbase + r;
        if (row >= nrows) break;
        float inv = 1.0f / (ldeg[r] + 1e-8f);
        msg[(size_t)row * DIM + lane]      = ls[r * DIM + lane]      * inv;
        msg[(size_t)row * DIM + lane + 64] = ls[r * DIM + lane + 64] * inv;
    }
}

// ---------------- MLP: 32 rows/block, LDS-blocked GEMM ----------------
__global__ __launch_bounds__(256, 2) void mlp_kernel(
    const float* __restrict__ selfemb, const float* __restrict__ msg,
    const float* __restrict__ w1, const float* __restrict__ b1,
    const float* __restrict__ g1, const float* __restrict__ be1,
    const float* __restrict__ w2, const float* __restrict__ b2,
    const float* __restrict__ g2, const float* __restrict__ be2,
    float* __restrict__ out)
{
    __shared__ float lds[16384];          // 64 KB
    float* xs = lds;                      // [32][256]
    float* ws = lds + 8192;               // w1 k-tile [64][128], later w2 [128][64]
    float* hs = lds;                      // [32][132] aliases xs

    int t = threadIdx.x;
    int rowbase = blockIdx.x * 32;

    #pragma unroll
    for (int i = 0; i < 8; ++i) {
        int li = i * 1024 + t * 4;
        int row = li >> 8;
        int col = li & 255;
        float4 v;
        if (col < 128) v = *(const float4*)&selfemb[(size_t)(rowbase + row) * DIM + col];
        else           v = *(const float4*)&msg[(size_t)(rowbase + row) * DIM + (col - 128)];
        *(float4*)&xs[li] = v;
    }
    __syncthreads();

    int ct = t & 31;
    int rt = t >> 5;
    int c0 = ct * 4;
    int r0 = rt * 4;

    float acc[4][4];
    {
        float4 bb = *(const float4*)&b1[c0];
        #pragma unroll
        for (int r = 0; r < 4; ++r) {
            acc[r][0] = bb.x; acc[r][1] = bb.y; acc[r][2] = bb.z; acc[r][3] = bb.w;
        }
    }

    for (int kt = 0; kt < 4; ++kt) {
        #pragma unroll
        for (int i = 0; i < 8; ++i) {
            int li = i * 1024 + t * 4;
            *(float4*)&ws[li] = *(const float4*)&w1[kt * 8192 + li];
        }
        __syncthreads();

        #pragma unroll 4
        for (int k = 0; k < 64; k += 4) {
            float4 wa = *(float4*)&ws[(k    ) * 128 + c0];
            float4 wb = *(float4*)&ws[(k + 1) * 128 + c0];
            float4 wc = *(float4*)&ws[(k + 2) * 128 + c0];
            float4 wd = *(float4*)&ws[(k + 3) * 128 + c0];
            #pragma unroll
            for (int r = 0; r < 4; ++r) {
                float4 x4 = *(float4*)&xs[(r0 + r) * 256 + kt * 64 + k];
                acc[r][0] += x4.x * wa.x + x4.y * wb.x + x4.z * wc.x + x4.w * wd.x;
                acc[r][1] += x4.x * wa.y + x4.y * wb.y + x4.z * wc.y + x4.w * wd.y;
                acc[r][2] += x4.x * wa.z + x4.y * wb.z + x4.z * wc.z + x4.w * wd.z;
                acc[r][3] += x4.x * wa.w + x4.y * wb.w + x4.z * wc.w + x4.w * wd.w;
            }
        }
        __syncthreads();
    }

    {
        float4 gg = *(const float4*)&g1[c0];
        float4 bb = *(const float4*)&be1[c0];
        #pragma unroll
        for (int r = 0; r < 4; ++r) {
            float s = acc[r][0] + acc[r][1] + acc[r][2] + acc[r][3];
            float q = acc[r][0]*acc[r][0] + acc[r][1]*acc[r][1]
                    + acc[r][2]*acc[r][2] + acc[r][3]*acc[r][3];
            #pragma unroll
            for (int m = 16; m; m >>= 1) {
                s += __shfl_xor(s, m);
                q += __shfl_xor(q, m);
            }
            float mu  = s * (1.0f / 128.0f);
            float var = q * (1.0f / 128.0f) - mu * mu;
            float rstd = rsqrtf(var + 1e-5f);
            float4 h;
            h.x = fmaxf((acc[r][0] - mu) * rstd * gg.x + bb.x, 0.f);
            h.y = fmaxf((acc[r][1] - mu) * rstd * gg.y + bb.y, 0.f);
            h.z = fmaxf((acc[r][2] - mu) * rstd * gg.z + bb.z, 0.f);
            h.w = fmaxf((acc[r][3] - mu) * rstd * gg.w + bb.w, 0.f);
            *(float4*)&hs[(r0 + r) * 132 + c0] = h;
        }
    }
    __syncthreads();

    #pragma unroll
    for (int i = 0; i < 8; ++i) {
        int li = i * 1024 + t * 4;
        *(float4*)&ws[li] = *(const float4*)&w2[li];
    }
    __syncthreads();

    int ct2 = t & 15;
    int rt2 = t >> 4;
    int c2 = ct2 * 4;
    int r2 = rt2 * 2;

    float acc2[2][4];
    {
        float4 bb = *(const float4*)&b2[c2];
        #pragma unroll
        for (int r = 0; r < 2; ++r) {
            acc2[r][0] = bb.x; acc2[r][1] = bb.y; acc2[r][2] = bb.z; acc2[r][3] = bb.w;
        }
    }

    #pragma unroll 4
    for (int k = 0; k < 128; k += 4) {
        float4 wa = *(float4*)&ws[(k    ) * 64 + c2];
        float4 wb = *(float4*)&ws[(k + 1) * 64 + c2];
        float4 wc = *(float4*)&ws[(k + 2) * 64 + c2];
        float4 wd = *(float4*)&ws[(k + 3) * 64 + c2];
        #pragma unroll
        for (int r = 0; r < 2; ++r) {
            float4 x4 = *(float4*)&hs[(r2 + r) * 132 + k];
            acc2[r][0] += x4.x * wa.x + x4.y * wb.x + x4.z * wc.x + x4.w * wd.x;
            acc2[r][1] += x4.x * wa.y + x4.y * wb.y + x4.z * wc.y + x4.w * wd.y;
            acc2[r][2] += x4.x * wa.z + x4.y * wb.z + x4.z * wc.z + x4.w * wd.z;
            acc2[r][3] += x4.x * wa.w + x4.y * wb.w + x4.z * wc.w + x4.w * wd.w;
        }
    }

    {
        float4 gg = *(const float4*)&g2[c2];
        float4 bb = *(const float4*)&be2[c2];
        #pragma unroll
        for (int r = 0; r < 2; ++r) {
            float s = acc2[r][0] + acc2[r][1] + acc2[r][2] + acc2[r][3];
            float q = acc2[r][0]*acc2[r][0] + acc2[r][1]*acc2[r][1]
                    + acc2[r][2]*acc2[r][2] + acc2[r][3]*acc2[r][3];
            #pragma unroll
            for (int m = 8; m; m >>= 1) {
                s += __shfl_xor(s, m);
                q += __shfl_xor(q, m);
            }
            float mu  = s * (1.0f / 64.0f);
            float var = q * (1.0f / 64.0f) - mu * mu;
            float rstd = rsqrtf(var + 1e-5f);
            float4 o;
            o.x = (acc2[r][0] - mu) * rstd * gg.x + bb.x;
            o.y = (acc2[r][1] - mu) * rstd * gg.y + bb.y;
            o.z = (acc2[r][2] - mu) * rstd * gg.z + bb.z;
            o.w = (acc2[r][3] - mu) * rstd * gg.w + bb.w;
            *(float4*)&out[(size_t)(rowbase + r2 + r) * OUTD + c2] = o;
        }
    }
}

extern "C" void kernel_launch(void* const* d_in, const int* in_sizes, int n_in,
                              void* d_out, int out_size, void* d_ws, size_t ws_size,
                              hipStream_t stream) {
    const int*   ep   = (const int*)d_in[0];
    const int*   ec   = (const int*)d_in[1];
    const float* ew   = (const float*)d_in[2];
    const float* pemb = (const float*)d_in[3];
    const float* cemb = (const float*)d_in[4];
    const float* w1p  = (const float*)d_in[5];
    const float* b1p  = (const float*)d_in[6];
    const float* g1p  = (const float*)d_in[7];
    const float* be1p = (const float*)d_in[8];
    const float* w2p  = (const float*)d_in[9];
    const float* b2p  = (const float*)d_in[10];
    const float* g2p  = (const float*)d_in[11];
    const float* be2p = (const float*)d_in[12];
    const float* w1c  = (const float*)d_in[13];
    const float* b1c  = (const float*)d_in[14];
    const float* g1c  = (const float*)d_in[15];
    const float* be1c = (const float*)d_in[16];
    const float* w2c  = (const float*)d_in[17];
    const float* b2c  = (const float*)d_in[18];
    const float* g2c  = (const float*)d_in[19];
    const float* be2c = (const float*)d_in[20];

    // ---- workspace layout (all sub-arrays 16B-aligned) ----
    int* wsi = (int*)d_ws;
    int* histbp  = wsi;                    // [1568]
    int* offbp   = histbp + PBINS_PAD;     // [1572] (need PBINS_PAD+1)
    int* curbp   = offbp + 1572;           // [1568]
    int* histbc  = curbp + PBINS_PAD;      // [320]
    int* offbc   = histbc + CBINS_PAD;     // [324] (need CBINS_PAD+1)
    int* curbc   = offbc + 324;            // [320]
    int* bsums_p = curbc + CBINS_PAD;      // [128]
    int* bsums_c = bsums_p + 128;          // [128]
    const int meta_ints = PBINS_PAD + 1572 + PBINS_PAD
                        + CBINS_PAD + 324 + CBINS_PAD + 256;   // 5928, %4==0
    uint2* binned_p = (uint2*)(wsi + meta_ints);   // NE
    uint2* binned_c = binned_p + NE;               // NE
    float* pmsg = (float*)(binned_c + NE);         // NP*DIM
    float* cmsg = pmsg + (size_t)NP * DIM;         // NC*DIM

    // zero meta (hists must be zero every call; scans overwrite the rest)
    zero4_kernel<<<32, 256, 0, stream>>>((float4*)wsi, (size_t)meta_ints / 4);

    int eblocks = (NE + 255) / 256;
    binhist_kernel<<<eblocks, 256, 0, stream>>>(ep, ec, histbp, histbc);

    const int NB_P = (PBINS_PAD + 1023) / 1024;   // 2
    const int NB_C = (CBINS_PAD + 1023) / 1024;   // 1
    scan1_kernel<<<NB_P, 256, 0, stream>>>(histbp, offbp, bsums_p, PBINS_PAD);
    scan2_kernel<<<1, 256, 0, stream>>>(bsums_p, NB_P);
    scan3_kernel<<<NB_P, 256, 0, stream>>>(offbp, curbp, bsums_p, PBINS_PAD, NE);
    scan1_kernel<<<NB_C, 256, 0, stream>>>(histbc, offbc, bsums_c, CBINS_PAD);
    scan2_kernel<<<1, 256, 0, stream>>>(bsums_c, NB_C);
    scan3_kernel<<<NB_C, 256, 0, stream>>>(offbc, curbc, bsums_c, CBINS_PAD, NE);

    binfill_kernel<<<eblocks, 256, 0, stream>>>(ep, ec, ew, curbp, curbc,
                                                binned_p, binned_c);

    aggbin_kernel<15, 0x7FFFu><<<PBINS, 256, 0, stream>>>(binned_p, offbp, cemb, pmsg, NP);
    aggbin_kernel<17, 0x1FFFFu><<<CBINS, 256, 0, stream>>>(binned_c, offbc, pemb, cmsg, NC);

    float* out_p = (float*)d_out;            // [NP, 64]
    float* out_c = out_p + (size_t)NP * OUTD;

    mlp_kernel<<<NP / 32, 256, 0, stream>>>(pemb, pmsg,
                                            w1p, b1p, g1p, be1p,
                                            w2p, b2p, g2p, be2p, out_p);
    mlp_kernel<<<NC / 32, 256, 0, stream>>>(cemb, cmsg,
                                            w1c, b1c, g1c, be1c,
                                            w2c, b2c, g2c, be2c, out_c);
}

// Round 5
// 2361.177 us; speedup vs baseline: 2.3667x; 2.3667x over previous
//
#include <hip/hip_runtime.h>
#include <cstddef>

#define NP 100000
#define NC 20000
#define NE 2000000
#define DIM 128
#define HID 128
#define OUTD 64

#define PBINS 1563        // ceil(NP/64)
#define CBINS 313         // ceil(NC/64)
#define PBINS_PAD 1568
#define CBINS_PAD 320

// ---------------- zero workspace region ----------------
__global__ void zero4_kernel(float4* p, size_t n4) {
    size_t i = blockIdx.x * (size_t)blockDim.x + threadIdx.x;
    size_t stride = (size_t)gridDim.x * blockDim.x;
    float4 z = make_float4(0.f, 0.f, 0.f, 0.f);
    for (; i < n4; i += stride) p[i] = z;
}

// ---------------- bin histogram ----------------
__global__ __launch_bounds__(256) void binhist_kernel(
    const int* __restrict__ ep, const int* __restrict__ ec,
    int* __restrict__ hbp, int* __restrict__ hbc)
{
    int e = blockIdx.x * 256 + threadIdx.x;
    if (e >= NE) return;
    atomicAdd(&hbp[ep[e] >> 6], 1);
    atomicAdd(&hbc[ec[e] >> 6], 1);
}

// ---------------- scan phase 1 ----------------
__global__ __launch_bounds__(256) void scan1_kernel(
    const int* __restrict__ in, int* __restrict__ out, int* __restrict__ bsums, int n)
{
    __shared__ int s[256];
    int t = threadIdx.x;
    int base = blockIdx.x * 1024 + t * 4;
    int4 v = make_int4(0, 0, 0, 0);
    if (base < n) v = *(const int4*)(in + base);
    int tsum = v.x + v.y + v.z + v.w;
    s[t] = tsum;
    __syncthreads();
    for (int off = 1; off < 256; off <<= 1) {
        int add = (t >= off) ? s[t - off] : 0;
        __syncthreads();
        s[t] += add;
        __syncthreads();
    }
    if (t == 255) bsums[blockIdx.x] = s[255];
    int tprefix = (t > 0) ? s[t - 1] : 0;
    if (base < n) {
        int4 o;
        o.x = tprefix;
        o.y = tprefix + v.x;
        o.z = tprefix + v.x + v.y;
        o.w = tprefix + v.x + v.y + v.z;
        *(int4*)(out + base) = o;
    }
}

// ---------------- scan phase 2 ----------------
__global__ __launch_bounds__(256) void scan2_kernel(int* __restrict__ bsums, int nb)
{
    __shared__ int s[256];
    int t = threadIdx.x;
    s[t] = (t < nb) ? bsums[t] : 0;
    __syncthreads();
    for (int off = 1; off < 256; off <<= 1) {
        int add = (t >= off) ? s[t - off] : 0;
        __syncthreads();
        s[t] += add;
        __syncthreads();
    }
    if (t < nb) bsums[t] = (t > 0) ? s[t - 1] : 0;
}

// ---------------- scan phase 3 ----------------
__global__ __launch_bounds__(256) void scan3_kernel(
    int* __restrict__ out, int* __restrict__ cur, const int* __restrict__ bsums,
    int n, int total)
{
    int t = threadIdx.x;
    int base = blockIdx.x * 1024 + t * 4;
    if (base < n) {
        int add = bsums[blockIdx.x];
        int4 v = *(const int4*)(out + base);
        v.x += add; v.y += add; v.z += add; v.w += add;
        *(int4*)(out + base) = v;
        *(int4*)(cur + base) = v;
    }
    if (blockIdx.x == 0 && t == 0) out[n] = total;
}

// ---------------- fill binned edge lists (packed key + weight) ----------------
// P-direction key: (p<<15)|c   (p<2^17, c<2^15);  C-direction key: (c<<17)|p
__global__ __launch_bounds__(256) void binfill_kernel(
    const int* __restrict__ ep, const int* __restrict__ ec, const float* __restrict__ ew,
    int* __restrict__ curp, int* __restrict__ curc,
    uint2* __restrict__ bp, uint2* __restrict__ bc)
{
    int e = blockIdx.x * 256 + threadIdx.x;
    if (e >= NE) return;
    unsigned p = (unsigned)ep[e];
    unsigned c = (unsigned)ec[e];
    unsigned wb = __float_as_uint(ew[e]);
    int pos = atomicAdd(&curp[p >> 6], 1);
    bp[pos] = make_uint2((p << 15) | c, wb);
    int pos2 = atomicAdd(&curc[c >> 6], 1);
    bc[pos2] = make_uint2((c << 17) | p, wb);
}

// ---------------- within-bin counting sort -> row-sorted edges + per-row CSR ----------------
template<int SHIFT, unsigned NMASK>
__global__ __launch_bounds__(256) void binsort_kernel(
    const uint2* __restrict__ binned, const int* __restrict__ boff,
    int2* __restrict__ sorted, int* __restrict__ rowoff, int nbins)
{
    __shared__ int cnt[64];
    __shared__ int cur[64];
    int t = threadIdx.x;
    int b = blockIdx.x;
    if (t < 64) cnt[t] = 0;
    __syncthreads();
    int start = boff[b];
    int end   = boff[b + 1];
    for (int j = start + t; j < end; j += 256) {
        unsigned key = binned[j].x;
        atomicAdd(&cnt[(key >> SHIFT) & 63u], 1);   // LDS int atomic: native ds_add
    }
    __syncthreads();
    if (t == 0) {
        int run = 0;
        #pragma unroll
        for (int r = 0; r < 64; ++r) { cur[r] = run; run += cnt[r]; }
    }
    __syncthreads();
    if (t < 64) rowoff[b * 64 + t] = start + cur[t];
    if (b == nbins - 1 && t == 0) rowoff[nbins * 64] = end;   // seal: == NE
    __syncthreads();   // all cur[] reads done before pass-2 mutates them
    for (int j = start + t; j < end; j += 256) {
        uint2 v = binned[j];
        int local = (int)((v.x >> SHIFT) & 63u);
        int pos = atomicAdd(&cur[local], 1);
        sorted[start + pos] = make_int2((int)(v.x & NMASK), (int)v.y);
    }
}

// ---------------- aggregate: wave per row (atomic-free) ----------------
__global__ __launch_bounds__(256) void agg_kernel(
    const int2* __restrict__ sorted, const int* __restrict__ off,
    const float* __restrict__ nbremb, float* __restrict__ msg)
{
    int wave = threadIdx.x >> 6;
    int lane = threadIdx.x & 63;
    int row = blockIdx.x * 4 + wave;   // grid sized exactly
    int start = off[row];
    int end   = off[row + 1];
    float acc0 = 0.f, acc1 = 0.f, deg = 0.f;
    for (int j = start; j < end; ++j) {
        int2 v = sorted[j];
        float w = __int_as_float(v.y);
        const float* nrow = nbremb + (size_t)v.x * DIM;
        deg  += w;
        acc0 += w * nrow[lane];
        acc1 += w * nrow[lane + 64];
    }
    float inv = 1.0f / (deg + 1e-8f);
    msg[(size_t)row * DIM + lane]      = acc0 * inv;
    msg[(size_t)row * DIM + lane + 64] = acc1 * inv;
}

// ---------------- MLP: 32 rows/block, LDS-blocked GEMM ----------------
__global__ __launch_bounds__(256, 2) void mlp_kernel(
    const float* __restrict__ selfemb, const float* __restrict__ msg,
    const float* __restrict__ w1, const float* __restrict__ b1,
    const float* __restrict__ g1, const float* __restrict__ be1,
    const float* __restrict__ w2, const float* __restrict__ b2,
    const float* __restrict__ g2, const float* __restrict__ be2,
    float* __restrict__ out)
{
    __shared__ float lds[16384];          // 64 KB
    float* xs = lds;                      // [32][256]
    float* ws = lds + 8192;               // w1 k-tile [64][128], later w2 [128][64]
    float* hs = lds;                      // [32][132] aliases xs

    int t = threadIdx.x;
    int rowbase = blockIdx.x * 32;

    #pragma unroll
    for (int i = 0; i < 8; ++i) {
        int li = i * 1024 + t * 4;
        int row = li >> 8;
        int col = li & 255;
        float4 v;
        if (col < 128) v = *(const float4*)&selfemb[(size_t)(rowbase + row) * DIM + col];
        else           v = *(const float4*)&msg[(size_t)(rowbase + row) * DIM + (col - 128)];
        *(float4*)&xs[li] = v;
    }
    __syncthreads();

    int ct = t & 31;
    int rt = t >> 5;
    int c0 = ct * 4;
    int r0 = rt * 4;

    float acc[4][4];
    {
        float4 bb = *(const float4*)&b1[c0];
        #pragma unroll
        for (int r = 0; r < 4; ++r) {
            acc[r][0] = bb.x; acc[r][1] = bb.y; acc[r][2] = bb.z; acc[r][3] = bb.w;
        }
    }

    for (int kt = 0; kt < 4; ++kt) {
        #pragma unroll
        for (int i = 0; i < 8; ++i) {
            int li = i * 1024 + t * 4;
            *(float4*)&ws[li] = *(const float4*)&w1[kt * 8192 + li];
        }
        __syncthreads();

        #pragma unroll 4
        for (int k = 0; k < 64; k += 4) {
            float4 wa = *(float4*)&ws[(k    ) * 128 + c0];
            float4 wb = *(float4*)&ws[(k + 1) * 128 + c0];
            float4 wc = *(float4*)&ws[(k + 2) * 128 + c0];
            float4 wd = *(float4*)&ws[(k + 3) * 128 + c0];
            #pragma unroll
            for (int r = 0; r < 4; ++r) {
                float4 x4 = *(float4*)&xs[(r0 + r) * 256 + kt * 64 + k];
                acc[r][0] += x4.x * wa.x + x4.y * wb.x + x4.z * wc.x + x4.w * wd.x;
                acc[r][1] += x4.x * wa.y + x4.y * wb.y + x4.z * wc.y + x4.w * wd.y;
                acc[r][2] += x4.x * wa.z + x4.y * wb.z + x4.z * wc.z + x4.w * wd.z;
                acc[r][3] += x4.x * wa.w + x4.y * wb.w + x4.z * wc.w + x4.w * wd.w;
            }
        }
        __syncthreads();
    }

    {
        float4 gg = *(const float4*)&g1[c0];
        float4 bb = *(const float4*)&be1[c0];
        #pragma unroll
        for (int r = 0; r < 4; ++r) {
            float s = acc[r][0] + acc[r][1] + acc[r][2] + acc[r][3];
            float q = acc[r][0]*acc[r][0] + acc[r][1]*acc[r][1]
                    + acc[r][2]*acc[r][2] + acc[r][3]*acc[r][3];
            #pragma unroll
            for (int m = 16; m; m >>= 1) {
                s += __shfl_xor(s, m);
                q += __shfl_xor(q, m);
            }
            float mu  = s * (1.0f / 128.0f);
            float var = q * (1.0f / 128.0f) - mu * mu;
            float rstd = rsqrtf(var + 1e-5f);
            float4 h;
            h.x = fmaxf((acc[r][0] - mu) * rstd * gg.x + bb.x, 0.f);
            h.y = fmaxf((acc[r][1] - mu) * rstd * gg.y + bb.y, 0.f);
            h.z = fmaxf((acc[r][2] - mu) * rstd * gg.z + bb.z, 0.f);
            h.w = fmaxf((acc[r][3] - mu) * rstd * gg.w + bb.w, 0.f);
            *(float4*)&hs[(r0 + r) * 132 + c0] = h;
        }
    }
    __syncthreads();

    #pragma unroll
    for (int i = 0; i < 8; ++i) {
        int li = i * 1024 + t * 4;
        *(float4*)&ws[li] = *(const float4*)&w2[li];
    }
    __syncthreads();

    int ct2 = t & 15;
    int rt2 = t >> 4;
    int c2 = ct2 * 4;
    int r2 = rt2 * 2;

    float acc2[2][4];
    {
        float4 bb = *(const float4*)&b2[c2];
        #pragma unroll
        for (int r = 0; r < 2; ++r) {
            acc2[r][0] = bb.x; acc2[r][1] = bb.y; acc2[r][2] = bb.z; acc2[r][3] = bb.w;
        }
    }

    #pragma unroll 4
    for (int k = 0; k < 128; k += 4) {
        float4 wa = *(float4*)&ws[(k    ) * 64 + c2];
        float4 wb = *(float4*)&ws[(k + 1) * 64 + c2];
        float4 wc = *(float4*)&ws[(k + 2) * 64 + c2];
        float4 wd = *(float4*)&ws[(k + 3) * 64 + c2];
        #pragma unroll
        for (int r = 0; r < 2; ++r) {
            float4 x4 = *(float4*)&hs[(r2 + r) * 132 + k];
            acc2[r][0] += x4.x * wa.x + x4.y * wb.x + x4.z * wc.x + x4.w * wd.x;
            acc2[r][1] += x4.x * wa.y + x4.y * wb.y + x4.z * wc.y + x4.w * wd.y;
            acc2[r][2] += x4.x * wa.z + x4.y * wb.z + x4.z * wc.z + x4.w * wd.z;
            acc2[r][3] += x4.x * wa.w + x4.y * wb.w + x4.z * wc.w + x4.w * wd.w;
        }
    }

    {
        float4 gg = *(const float4*)&g2[c2];
        float4 bb = *(const float4*)&be2[c2];
        #pragma unroll
        for (int r = 0; r < 2; ++r) {
            float s = acc2[r][0] + acc2[r][1] + acc2[r][2] + acc2[r][3];
            float q = acc2[r][0]*acc2[r][0] + acc2[r][1]*acc2[r][1]
                    + acc2[r][2]*acc2[r][2] + acc2[r][3]*acc2[r][3];
            #pragma unroll
            for (int m = 8; m; m >>= 1) {
                s += __shfl_xor(s, m);
                q += __shfl_xor(q, m);
            }
            float mu  = s * (1.0f / 64.0f);
            float var = q * (1.0f / 64.0f) - mu * mu;
            float rstd = rsqrtf(var + 1e-5f);
            float4 o;
            o.x = (acc2[r][0] - mu) * rstd * gg.x + bb.x;
            o.y = (acc2[r][1] - mu) * rstd * gg.y + bb.y;
            o.z = (acc2[r][2] - mu) * rstd * gg.z + bb.z;
            o.w = (acc2[r][3] - mu) * rstd * gg.w + bb.w;
            *(float4*)&out[(size_t)(rowbase + r2 + r) * OUTD + c2] = o;
        }
    }
}

extern "C" void kernel_launch(void* const* d_in, const int* in_sizes, int n_in,
                              void* d_out, int out_size, void* d_ws, size_t ws_size,
                              hipStream_t stream) {
    const int*   ep   = (const int*)d_in[0];
    const int*   ec   = (const int*)d_in[1];
    const float* ew   = (const float*)d_in[2];
    const float* pemb = (const float*)d_in[3];
    const float* cemb = (const float*)d_in[4];
    const float* w1p  = (const float*)d_in[5];
    const float* b1p  = (const float*)d_in[6];
    const float* g1p  = (const float*)d_in[7];
    const float* be1p = (const float*)d_in[8];
    const float* w2p  = (const float*)d_in[9];
    const float* b2p  = (const float*)d_in[10];
    const float* g2p  = (const float*)d_in[11];
    const float* be2p = (const float*)d_in[12];
    const float* w1c  = (const float*)d_in[13];
    const float* b1c  = (const float*)d_in[14];
    const float* g1c  = (const float*)d_in[15];
    const float* be1c = (const float*)d_in[16];
    const float* w2c  = (const float*)d_in[17];
    const float* b2c  = (const float*)d_in[18];
    const float* g2c  = (const float*)d_in[19];
    const float* be2c = (const float*)d_in[20];

    // ---- workspace layout ----
    int* wsi = (int*)d_ws;
    int* histbp  = wsi;                    // [1568]
    int* offbp   = histbp + PBINS_PAD;     // [1572]
    int* curbp   = offbp + 1572;           // [1568]
    int* histbc  = curbp + PBINS_PAD;      // [320]
    int* offbc   = histbc + CBINS_PAD;     // [324]
    int* curbc   = offbc + 324;            // [320]
    int* bsums_p = curbc + CBINS_PAD;      // [128]
    int* bsums_c = bsums_p + 128;          // [128]
    const int bin_meta = PBINS_PAD + 1572 + PBINS_PAD
                       + CBINS_PAD + 324 + CBINS_PAD + 256;   // 5928
    int* rowoff_p = wsi + bin_meta;        // [100036] (PBINS*64+1 = 100033)
    int* rowoff_c = rowoff_p + 100036;     // [20036]  (CBINS*64+1 = 20033)
    const int meta_ints = bin_meta + 100036 + 20036;          // 126000, %4==0

    // big regions (lifetimes stream-ordered; aliases noted)
    uint2* binned_p = (uint2*)(wsi + meta_ints);   // R1: NE uint2
    int2*  sorted_p = (int2*)(binned_p + NE);      // R3: NE int2
    float* pmsg     = (float*)(sorted_p + NE);     // msg zone: NP*DIM floats
    uint2* binned_c = (uint2*)pmsg;                //   aliases pmsg[0..4M) - consumed before agg_p writes
    int2*  sorted_c = (int2*)binned_p;             //   aliases R1 - binned_p consumed by binsort_p first
    float* cmsg     = pmsg + (size_t)NP * DIM;     // NC*DIM floats

    // zero bin-meta only (hists+cursors; row offsets are fully overwritten)
    zero4_kernel<<<32, 256, 0, stream>>>((float4*)wsi, (size_t)bin_meta / 4);

    int eblocks = (NE + 255) / 256;
    binhist_kernel<<<eblocks, 256, 0, stream>>>(ep, ec, histbp, histbc);

    const int NB_P = (PBINS_PAD + 1023) / 1024;   // 2
    const int NB_C = (CBINS_PAD + 1023) / 1024;   // 1
    scan1_kernel<<<NB_P, 256, 0, stream>>>(histbp, offbp, bsums_p, PBINS_PAD);
    scan2_kernel<<<1, 256, 0, stream>>>(bsums_p, NB_P);
    scan3_kernel<<<NB_P, 256, 0, stream>>>(offbp, curbp, bsums_p, PBINS_PAD, NE);
    scan1_kernel<<<NB_C, 256, 0, stream>>>(histbc, offbc, bsums_c, CBINS_PAD);
    scan2_kernel<<<1, 256, 0, stream>>>(bsums_c, NB_C);
    scan3_kernel<<<NB_C, 256, 0, stream>>>(offbc, curbc, bsums_c, CBINS_PAD, NE);

    binfill_kernel<<<eblocks, 256, 0, stream>>>(ep, ec, ew, curbp, curbc,
                                                binned_p, binned_c);

    binsort_kernel<15, 0x7FFFu><<<PBINS, 256, 0, stream>>>(binned_p, offbp,
                                                           sorted_p, rowoff_p, PBINS);
    binsort_kernel<17, 0x1FFFFu><<<CBINS, 256, 0, stream>>>(binned_c, offbc,
                                                            sorted_c, rowoff_c, CBINS);

    agg_kernel<<<NP / 4, 256, 0, stream>>>(sorted_p, rowoff_p, cemb, pmsg);
    agg_kernel<<<NC / 4, 256, 0, stream>>>(sorted_c, rowoff_c, pemb, cmsg);

    float* out_p = (float*)d_out;            // [NP, 64]
    float* out_c = out_p + (size_t)NP * OUTD;

    mlp_kernel<<<NP / 32, 256, 0, stream>>>(pemb, pmsg,
                                            w1p, b1p, g1p, be1p,
                                            w2p, b2p, g2p, be2p, out_p);
    mlp_kernel<<<NC / 32, 256, 0, stream>>>(cemb, cmsg,
                                            w1c, b1c, g1c, be1c,
                                            w2c, b2c, g2c, be2c, out_c);
}

// Round 6
// 810.254 us; speedup vs baseline: 6.8968x; 2.9141x over previous
//
#include <hip/hip_runtime.h>
#include <cstddef>

#define NP 100000
#define NC 20000
#define NE 2000000
#define DIM 128
#define HID 128
#define OUTD 64

#define PBK 98      // ceil(NP/1024) buckets of 1024 providers
#define CBK 79      // ceil(NC/256)  buckets of 256 codes
#define CHUNK 4096  // edges per part-block

// ---------------- zero (bucket histograms only) ----------------
__global__ void zero4_kernel(float4* p, size_t n4) {
    size_t i = blockIdx.x * (size_t)blockDim.x + threadIdx.x;
    size_t stride = (size_t)gridDim.x * blockDim.x;
    float4 z = make_float4(0.f, 0.f, 0.f, 0.f);
    for (; i < n4; i += stride) p[i] = z;
}

// ---------------- bucket histogram (LDS-aggregated; padded global counters) ----------------
__global__ __launch_bounds__(256) void bhist_kernel(
    const int* __restrict__ ep, const int* __restrict__ ec,
    int* __restrict__ PH, int* __restrict__ CH)
{
    __shared__ int hp[PBK];
    __shared__ int hc[CBK];
    int t = threadIdx.x;
    if (t < PBK) hp[t] = 0;
    if (t < CBK) hc[t] = 0;
    __syncthreads();
    for (int e = blockIdx.x * 256 + t; e < NE; e += 256 * 256) {
        atomicAdd(&hp[ep[e] >> 10], 1);
        atomicAdd(&hc[ec[e] >> 8], 1);
    }
    __syncthreads();
    if (t < PBK) atomicAdd(&PH[t * 16], hp[t]);
    if (t < CBK) atomicAdd(&CH[t * 16], hc[t]);
}

// ---------------- bucket scans (single block, both directions) ----------------
__global__ __launch_bounds__(256) void bscan_kernel(
    const int* __restrict__ PH, const int* __restrict__ CH,
    int* __restrict__ POFF, int* __restrict__ COFF,
    int* __restrict__ PCUR, int* __restrict__ CCUR)
{
    __shared__ int s[256];
    int t = threadIdx.x;
    s[t] = (t < PBK) ? PH[t * 16] : 0;
    __syncthreads();
    for (int off = 1; off < 256; off <<= 1) {
        int a = (t >= off) ? s[t - off] : 0;
        __syncthreads();
        s[t] += a;
        __syncthreads();
    }
    int excl = t ? s[t - 1] : 0;
    if (t < PBK) { POFF[t] = excl; PCUR[t * 16] = excl; }
    if (t == 0) POFF[PBK] = NE;
    __syncthreads();
    s[t] = (t < CBK) ? CH[t * 16] : 0;
    __syncthreads();
    for (int off = 1; off < 256; off <<= 1) {
        int a = (t >= off) ? s[t - off] : 0;
        __syncthreads();
        s[t] += a;
        __syncthreads();
    }
    excl = t ? s[t - 1] : 0;
    if (t < CBK) { COFF[t] = excl; CCUR[t * 16] = excl; }
    if (t == 0) COFF[CBK] = NE;
}

// ---------------- pass A: partition into buckets with per-block range reservation ----------------
// P record: ((p&1023)<<15)|c ; C record: ((c&255)<<17)|p ; .y = weight bits
__global__ __launch_bounds__(256) void part_kernel(
    const int* __restrict__ ep, const int* __restrict__ ec, const float* __restrict__ ew,
    int* __restrict__ PCUR, int* __restrict__ CCUR,
    uint2* __restrict__ Ap, uint2* __restrict__ Ac)
{
    __shared__ int cp[PBK], bp_[PBK], cc[CBK], bc_[CBK];
    int t = threadIdx.x;
    int base = blockIdx.x * CHUNK;
    if (t < PBK) cp[t] = 0;
    if (t < CBK) cc[t] = 0;
    __syncthreads();
    #pragma unroll
    for (int i = 0; i < CHUNK / 256; ++i) {
        int e = base + i * 256 + t;
        if (e < NE) {
            atomicAdd(&cp[ep[e] >> 10], 1);
            atomicAdd(&cc[ec[e] >> 8], 1);
        }
    }
    __syncthreads();
    if (t < PBK) { bp_[t] = atomicAdd(&PCUR[t * 16], cp[t]); cp[t] = 0; }
    if (t < CBK) { bc_[t] = atomicAdd(&CCUR[t * 16], cc[t]); cc[t] = 0; }
    __syncthreads();
    #pragma unroll
    for (int i = 0; i < CHUNK / 256; ++i) {
        int e = base + i * 256 + t;
        if (e < NE) {
            unsigned p = (unsigned)ep[e];
            unsigned c = (unsigned)ec[e];
            unsigned wb = __float_as_uint(ew[e]);
            int b1 = p >> 10;
            int pos = bp_[b1] + atomicAdd(&cp[b1], 1);
            Ap[pos] = make_uint2(((p & 1023u) << 15) | c, wb);
            int b2 = c >> 8;
            int pos2 = bc_[b2] + atomicAdd(&cc[b2], 1);
            Ac[pos2] = make_uint2(((c & 255u) << 17) | p, wb);
        }
    }
}

// ---------------- pass B: within-bucket counting sort + per-row CSR ----------------
template<int LOCALS, int SHIFT, unsigned NMASK>
__global__ __launch_bounds__(256) void bsort_kernel(
    const uint2* __restrict__ A, const int* __restrict__ OFF,
    int2* __restrict__ S, int* __restrict__ rowoff, int nrows_total, int nbins)
{
    __shared__ int cnt[LOCALS];
    __shared__ int tsum[256];
    constexpr int NL = LOCALS / 256;
    int t = threadIdx.x;
    int b = blockIdx.x;
    int s0 = OFF[b], e0 = OFF[b + 1];
    #pragma unroll
    for (int k = 0; k < NL; ++k) cnt[t * NL + k] = 0;
    __syncthreads();
    for (int j = s0 + t; j < e0; j += 256)
        atomicAdd(&cnt[A[j].x >> SHIFT], 1);
    __syncthreads();
    int pre[NL];
    int run = 0;
    #pragma unroll
    for (int k = 0; k < NL; ++k) { pre[k] = run; run += cnt[t * NL + k]; }
    tsum[t] = run;
    __syncthreads();
    for (int off = 1; off < 256; off <<= 1) {
        int a = (t >= off) ? tsum[t - off] : 0;
        __syncthreads();
        tsum[t] += a;
        __syncthreads();
    }
    int excl = t ? tsum[t - 1] : 0;
    #pragma unroll
    for (int k = 0; k < NL; ++k) cnt[t * NL + k] = excl + pre[k];
    __syncthreads();
    int rowbase = b * LOCALS;
    #pragma unroll
    for (int k = 0; k < NL; ++k) {
        int r = t * NL + k;
        if (rowbase + r < nrows_total) rowoff[rowbase + r] = s0 + cnt[r];
    }
    if (b == nbins - 1 && t == 0) rowoff[nrows_total] = e0;
    __syncthreads();   // rowoff reads of cnt complete before scatter mutates cnt
    for (int j = s0 + t; j < e0; j += 256) {
        uint2 v = A[j];
        int loc = (int)(v.x >> SHIFT);
        int pos = s0 + atomicAdd(&cnt[loc], 1);
        S[pos] = make_int2((int)(v.x & NMASK), (int)v.y);
    }
}

// ---------------- aggregate: wave per row (atomic-free) ----------------
__global__ __launch_bounds__(256) void agg_kernel(
    const int2* __restrict__ sorted, const int* __restrict__ off,
    const float* __restrict__ nbremb, float* __restrict__ msg)
{
    int wave = threadIdx.x >> 6;
    int lane = threadIdx.x & 63;
    int row = blockIdx.x * 4 + wave;   // grid sized exactly
    int start = off[row];
    int end   = off[row + 1];
    float acc0 = 0.f, acc1 = 0.f, deg = 0.f;
    for (int j = start; j < end; ++j) {
        int2 v = sorted[j];
        float w = __int_as_float(v.y);
        const float* nrow = nbremb + (size_t)v.x * DIM;
        deg  += w;
        acc0 += w * nrow[lane];
        acc1 += w * nrow[lane + 64];
    }
    float inv = 1.0f / (deg + 1e-8f);
    msg[(size_t)row * DIM + lane]      = acc0 * inv;
    msg[(size_t)row * DIM + lane + 64] = acc1 * inv;
}

// ---------------- MLP: 32 rows/block, LDS-blocked GEMM ----------------
__global__ __launch_bounds__(256, 2) void mlp_kernel(
    const float* __restrict__ selfemb, const float* __restrict__ msg,
    const float* __restrict__ w1, const float* __restrict__ b1,
    const float* __restrict__ g1, const float* __restrict__ be1,
    const float* __restrict__ w2, const float* __restrict__ b2,
    const float* __restrict__ g2, const float* __restrict__ be2,
    float* __restrict__ out)
{
    __shared__ float lds[16384];          // 64 KB
    float* xs = lds;                      // [32][256]
    float* ws = lds + 8192;               // w1 k-tile [64][128], later w2 [128][64]
    float* hs = lds;                      // [32][132] aliases xs

    int t = threadIdx.x;
    int rowbase = blockIdx.x * 32;

    #pragma unroll
    for (int i = 0; i < 8; ++i) {
        int li = i * 1024 + t * 4;
        int row = li >> 8;
        int col = li & 255;
        float4 v;
        if (col < 128) v = *(const float4*)&selfemb[(size_t)(rowbase + row) * DIM + col];
        else           v = *(const float4*)&msg[(size_t)(rowbase + row) * DIM + (col - 128)];
        *(float4*)&xs[li] = v;
    }
    __syncthreads();

    int ct = t & 31;
    int rt = t >> 5;
    int c0 = ct * 4;
    int r0 = rt * 4;

    float acc[4][4];
    {
        float4 bb = *(const float4*)&b1[c0];
        #pragma unroll
        for (int r = 0; r < 4; ++r) {
            acc[r][0] = bb.x; acc[r][1] = bb.y; acc[r][2] = bb.z; acc[r][3] = bb.w;
        }
    }

    for (int kt = 0; kt < 4; ++kt) {
        #pragma unroll
        for (int i = 0; i < 8; ++i) {
            int li = i * 1024 + t * 4;
            *(float4*)&ws[li] = *(const float4*)&w1[kt * 8192 + li];
        }
        __syncthreads();

        #pragma unroll 4
        for (int k = 0; k < 64; k += 4) {
            float4 wa = *(float4*)&ws[(k    ) * 128 + c0];
            float4 wb = *(float4*)&ws[(k + 1) * 128 + c0];
            float4 wc = *(float4*)&ws[(k + 2) * 128 + c0];
            float4 wd = *(float4*)&ws[(k + 3) * 128 + c0];
            #pragma unroll
            for (int r = 0; r < 4; ++r) {
                float4 x4 = *(float4*)&xs[(r0 + r) * 256 + kt * 64 + k];
                acc[r][0] += x4.x * wa.x + x4.y * wb.x + x4.z * wc.x + x4.w * wd.x;
                acc[r][1] += x4.x * wa.y + x4.y * wb.y + x4.z * wc.y + x4.w * wd.y;
                acc[r][2] += x4.x * wa.z + x4.y * wb.z + x4.z * wc.z + x4.w * wd.z;
                acc[r][3] += x4.x * wa.w + x4.y * wb.w + x4.z * wc.w + x4.w * wd.w;
            }
        }
        __syncthreads();
    }

    {
        float4 gg = *(const float4*)&g1[c0];
        float4 bb = *(const float4*)&be1[c0];
        #pragma unroll
        for (int r = 0; r < 4; ++r) {
            float s = acc[r][0] + acc[r][1] + acc[r][2] + acc[r][3];
            float q = acc[r][0]*acc[r][0] + acc[r][1]*acc[r][1]
                    + acc[r][2]*acc[r][2] + acc[r][3]*acc[r][3];
            #pragma unroll
            for (int m = 16; m; m >>= 1) {
                s += __shfl_xor(s, m);
                q += __shfl_xor(q, m);
            }
            float mu  = s * (1.0f / 128.0f);
            float var = q * (1.0f / 128.0f) - mu * mu;
            float rstd = rsqrtf(var + 1e-5f);
            float4 h;
            h.x = fmaxf((acc[r][0] - mu) * rstd * gg.x + bb.x, 0.f);
            h.y = fmaxf((acc[r][1] - mu) * rstd * gg.y + bb.y, 0.f);
            h.z = fmaxf((acc[r][2] - mu) * rstd * gg.z + bb.z, 0.f);
            h.w = fmaxf((acc[r][3] - mu) * rstd * gg.w + bb.w, 0.f);
            *(float4*)&hs[(r0 + r) * 132 + c0] = h;
        }
    }
    __syncthreads();

    #pragma unroll
    for (int i = 0; i < 8; ++i) {
        int li = i * 1024 + t * 4;
        *(float4*)&ws[li] = *(const float4*)&w2[li];
    }
    __syncthreads();

    int ct2 = t & 15;
    int rt2 = t >> 4;
    int c2 = ct2 * 4;
    int r2 = rt2 * 2;

    float acc2[2][4];
    {
        float4 bb = *(const float4*)&b2[c2];
        #pragma unroll
        for (int r = 0; r < 2; ++r) {
            acc2[r][0] = bb.x; acc2[r][1] = bb.y; acc2[r][2] = bb.z; acc2[r][3] = bb.w;
        }
    }

    #pragma unroll 4
    for (int k = 0; k < 128; k += 4) {
        float4 wa = *(float4*)&ws[(k    ) * 64 + c2];
        float4 wb = *(float4*)&ws[(k + 1) * 64 + c2];
        float4 wc = *(float4*)&ws[(k + 2) * 64 + c2];
        float4 wd = *(float4*)&ws[(k + 3) * 64 + c2];
        #pragma unroll
        for (int r = 0; r < 2; ++r) {
            float4 x4 = *(float4*)&hs[(r2 + r) * 132 + k];
            acc2[r][0] += x4.x * wa.x + x4.y * wb.x + x4.z * wc.x + x4.w * wd.x;
            acc2[r][1] += x4.x * wa.y + x4.y * wb.y + x4.z * wc.y + x4.w * wd.y;
            acc2[r][2] += x4.x * wa.z + x4.y * wb.z + x4.z * wc.z + x4.w * wd.z;
            acc2[r][3] += x4.x * wa.w + x4.y * wb.w + x4.z * wc.w + x4.w * wd.w;
        }
    }

    {
        float4 gg = *(const float4*)&g2[c2];
        float4 bb = *(const float4*)&be2[c2];
        #pragma unroll
        for (int r = 0; r < 2; ++r) {
            float s = acc2[r][0] + acc2[r][1] + acc2[r][2] + acc2[r][3];
            float q = acc2[r][0]*acc2[r][0] + acc2[r][1]*acc2[r][1]
                    + acc2[r][2]*acc2[r][2] + acc2[r][3]*acc2[r][3];
            #pragma unroll
            for (int m = 8; m; m >>= 1) {
                s += __shfl_xor(s, m);
                q += __shfl_xor(q, m);
            }
            float mu  = s * (1.0f / 64.0f);
            float var = q * (1.0f / 64.0f) - mu * mu;
            float rstd = rsqrtf(var + 1e-5f);
            float4 o;
            o.x = (acc2[r][0] - mu) * rstd * gg.x + bb.x;
            o.y = (acc2[r][1] - mu) * rstd * gg.y + bb.y;
            o.z = (acc2[r][2] - mu) * rstd * gg.z + bb.z;
            o.w = (acc2[r][3] - mu) * rstd * gg.w + bb.w;
            *(float4*)&out[(size_t)(rowbase + r2 + r) * OUTD + c2] = o;
        }
    }
}

extern "C" void kernel_launch(void* const* d_in, const int* in_sizes, int n_in,
                              void* d_out, int out_size, void* d_ws, size_t ws_size,
                              hipStream_t stream) {
    const int*   ep   = (const int*)d_in[0];
    const int*   ec   = (const int*)d_in[1];
    const float* ew   = (const float*)d_in[2];
    const float* pemb = (const float*)d_in[3];
    const float* cemb = (const float*)d_in[4];
    const float* w1p  = (const float*)d_in[5];
    const float* b1p  = (const float*)d_in[6];
    const float* g1p  = (const float*)d_in[7];
    const float* be1p = (const float*)d_in[8];
    const float* w2p  = (const float*)d_in[9];
    const float* b2p  = (const float*)d_in[10];
    const float* g2p  = (const float*)d_in[11];
    const float* be2p = (const float*)d_in[12];
    const float* w1c  = (const float*)d_in[13];
    const float* b1c  = (const float*)d_in[14];
    const float* g1c  = (const float*)d_in[15];
    const float* be1c = (const float*)d_in[16];
    const float* w2c  = (const float*)d_in[17];
    const float* b2c  = (const float*)d_in[18];
    const float* g2c  = (const float*)d_in[19];
    const float* be2c = (const float*)d_in[20];

    // ---- meta workspace (ints) ----
    int* wsi  = (int*)d_ws;
    int* PH   = wsi;               // [98*16]  zeroed every call
    int* CH   = PH + 1568;         // [79*16]  zeroed every call
    int* PCUR = CH + 1264;         // [98*16]  (written by bscan)
    int* CCUR = PCUR + 1568;       // [79*16]
    int* POFF = CCUR + 1264;       // [100] (need 99)
    int* COFF = POFF + 100;        // [84]  (need 80)
    int* rowoff_p = COFF + 84;         // [100004] (need 100001)
    int* rowoff_c = rowoff_p + 100004; // [20004]  (need 20001)
    const int zero_ints = 1568 + 1264;                       // 2832
    const int meta_ints = 2832 + 1568 + 1264 + 100 + 84 + 100004 + 20004; // 125856

    // ---- big regions (stream-ordered lifetimes; aliases noted) ----
    uint2* Ap = (uint2*)(wsi + meta_ints);   // NE  (pass A out, bsort_p in)
    int2*  Sp = (int2*)(Ap + NE);            // NE  (bsort_p out, agg_p in)
    uint2* Ac = (uint2*)(Sp + NE);           // NE  (pass A out, bsort_c in)
    int2*  Sc = (int2*)Ap;                   // aliases Ap (dead after bsort_p)
    float* pmsg = (float*)Ac;                // aliases Ac onward (dead after bsort_c)
    float* cmsg = pmsg + (size_t)NP * DIM;

    zero4_kernel<<<3, 256, 0, stream>>>((float4*)wsi, (size_t)zero_ints / 4);

    bhist_kernel<<<256, 256, 0, stream>>>(ep, ec, PH, CH);
    bscan_kernel<<<1, 256, 0, stream>>>(PH, CH, POFF, COFF, PCUR, CCUR);

    int pblocks = (NE + CHUNK - 1) / CHUNK;   // 489
    part_kernel<<<pblocks, 256, 0, stream>>>(ep, ec, ew, PCUR, CCUR, Ap, Ac);

    bsort_kernel<1024, 15, 0x7FFFu><<<PBK, 256, 0, stream>>>(Ap, POFF, Sp, rowoff_p, NP, PBK);
    bsort_kernel<256, 17, 0x1FFFFu><<<CBK, 256, 0, stream>>>(Ac, COFF, Sc, rowoff_c, NC, CBK);

    agg_kernel<<<NP / 4, 256, 0, stream>>>(Sp, rowoff_p, cemb, pmsg);
    agg_kernel<<<NC / 4, 256, 0, stream>>>(Sc, rowoff_c, pemb, cmsg);

    float* out_p = (float*)d_out;             // [NP, 64]
    float* out_c = out_p + (size_t)NP * OUTD; // [NC, 64]

    mlp_kernel<<<NP / 32, 256, 0, stream>>>(pemb, pmsg,
                                            w1p, b1p, g1p, be1p,
                                            w2p, b2p, g2p, be2p, out_p);
    mlp_kernel<<<NC / 32, 256, 0, stream>>>(cemb, cmsg,
                                            w1c, b1c, g1c, be1c,
                                            w2c, b2c, g2c, be2c, out_c);
}

// Round 7
// 598.482 us; speedup vs baseline: 9.3372x; 1.3538x over previous
//
#include <hip/hip_runtime.h>
#include <cstddef>

#define NP 100000
#define NC 20000
#define NE 2000000
#define DIM 128
#define HID 128
#define OUTD 64

#define PBK 98      // ceil(NP/1024) buckets of 1024 providers
#define CBK 79      // ceil(NC/256)  buckets of 256 codes
#define CHUNK 4096  // edges per part-block

typedef __attribute__((ext_vector_type(8))) short short8v;
typedef __attribute__((ext_vector_type(4))) float f32x4;

__device__ __forceinline__ unsigned f2bf(float f) {
    unsigned u = __float_as_uint(f);
    return (u + 0x7FFFu + ((u >> 16) & 1u)) >> 16;   // RNE
}
__device__ __forceinline__ float bf2f(unsigned s) {
    return __uint_as_float(s << 16);
}

// ---------------- zero (bucket histograms only) ----------------
__global__ void zero4_kernel(float4* p, size_t n4) {
    size_t i = blockIdx.x * (size_t)blockDim.x + threadIdx.x;
    size_t stride = (size_t)gridDim.x * blockDim.x;
    float4 z = make_float4(0.f, 0.f, 0.f, 0.f);
    for (; i < n4; i += stride) p[i] = z;
}

// ---------------- f32 -> bf16 conversion ----------------
__global__ void conv_kernel(const float4* __restrict__ in, uint2* __restrict__ outp, size_t n4) {
    size_t i = blockIdx.x * (size_t)blockDim.x + threadIdx.x;
    size_t st = (size_t)gridDim.x * blockDim.x;
    for (; i < n4; i += st) {
        float4 v = in[i];
        outp[i] = make_uint2(f2bf(v.x) | (f2bf(v.y) << 16),
                             f2bf(v.z) | (f2bf(v.w) << 16));
    }
}

// ---------------- prepack weights into MFMA A-fragment order ----------------
// packed[((mt*KT + ks)*64 + lane)*8 + j] = bf16( w[(ks*32 + (lane>>4)*8 + j)*M + mt*16 + (lane&15)] )
__device__ __forceinline__ void pack_one(const float* __restrict__ w, unsigned short* __restrict__ dst,
                                         int M, int KT, int idx) {
    int lane = idx & 63;
    int rest = idx >> 6;
    int ks = rest % KT;
    int mt = rest / KT;
    int m  = mt * 16 + (lane & 15);
    int kb = ks * 32 + ((lane >> 4) << 3);
    uint4 r;
    r.x = f2bf(w[(kb + 0) * M + m]) | (f2bf(w[(kb + 1) * M + m]) << 16);
    r.y = f2bf(w[(kb + 2) * M + m]) | (f2bf(w[(kb + 3) * M + m]) << 16);
    r.z = f2bf(w[(kb + 4) * M + m]) | (f2bf(w[(kb + 5) * M + m]) << 16);
    r.w = f2bf(w[(kb + 6) * M + m]) | (f2bf(w[(kb + 7) * M + m]) << 16);
    *(uint4*)(dst + (size_t)idx * 8) = r;
}
__global__ __launch_bounds__(256) void pack_kernel(
    const float* __restrict__ w1p, const float* __restrict__ w2p,
    const float* __restrict__ w1c, const float* __restrict__ w2c,
    unsigned short* __restrict__ d1p, unsigned short* __restrict__ d2p,
    unsigned short* __restrict__ d1c, unsigned short* __restrict__ d2c) {
    int idx = blockIdx.x * 256 + threadIdx.x;     // 0..10239
    if (idx < 4096)       pack_one(w1p, d1p, 128, 8, idx);
    else if (idx < 5120)  pack_one(w2p, d2p, 64, 4, idx - 4096);
    else if (idx < 9216)  pack_one(w1c, d1c, 128, 8, idx - 5120);
    else if (idx < 10240) pack_one(w2c, d2c, 64, 4, idx - 9216);
}

// ---------------- bucket histogram ----------------
__global__ __launch_bounds__(256) void bhist_kernel(
    const int* __restrict__ ep, const int* __restrict__ ec,
    int* __restrict__ PH, int* __restrict__ CH)
{
    __shared__ int hp[PBK];
    __shared__ int hc[CBK];
    int t = threadIdx.x;
    if (t < PBK) hp[t] = 0;
    if (t < CBK) hc[t] = 0;
    __syncthreads();
    for (int e = blockIdx.x * 256 + t; e < NE; e += 256 * 256) {
        atomicAdd(&hp[ep[e] >> 10], 1);
        atomicAdd(&hc[ec[e] >> 8], 1);
    }
    __syncthreads();
    if (t < PBK) atomicAdd(&PH[t * 16], hp[t]);
    if (t < CBK) atomicAdd(&CH[t * 16], hc[t]);
}

// ---------------- bucket scans ----------------
__global__ __launch_bounds__(256) void bscan_kernel(
    const int* __restrict__ PH, const int* __restrict__ CH,
    int* __restrict__ POFF, int* __restrict__ COFF,
    int* __restrict__ PCUR, int* __restrict__ CCUR)
{
    __shared__ int s[256];
    int t = threadIdx.x;
    s[t] = (t < PBK) ? PH[t * 16] : 0;
    __syncthreads();
    for (int off = 1; off < 256; off <<= 1) {
        int a = (t >= off) ? s[t - off] : 0;
        __syncthreads();
        s[t] += a;
        __syncthreads();
    }
    int excl = t ? s[t - 1] : 0;
    if (t < PBK) { POFF[t] = excl; PCUR[t * 16] = excl; }
    if (t == 0) POFF[PBK] = NE;
    __syncthreads();
    s[t] = (t < CBK) ? CH[t * 16] : 0;
    __syncthreads();
    for (int off = 1; off < 256; off <<= 1) {
        int a = (t >= off) ? s[t - off] : 0;
        __syncthreads();
        s[t] += a;
        __syncthreads();
    }
    excl = t ? s[t - 1] : 0;
    if (t < CBK) { COFF[t] = excl; CCUR[t * 16] = excl; }
    if (t == 0) COFF[CBK] = NE;
}

// ---------------- pass A: partition into buckets ----------------
__global__ __launch_bounds__(256) void part_kernel(
    const int* __restrict__ ep, const int* __restrict__ ec, const float* __restrict__ ew,
    int* __restrict__ PCUR, int* __restrict__ CCUR,
    uint2* __restrict__ Ap, uint2* __restrict__ Ac)
{
    __shared__ int cp[PBK], bp_[PBK], cc[CBK], bc_[CBK];
    int t = threadIdx.x;
    int base = blockIdx.x * CHUNK;
    if (t < PBK) cp[t] = 0;
    if (t < CBK) cc[t] = 0;
    __syncthreads();
    #pragma unroll
    for (int i = 0; i < CHUNK / 256; ++i) {
        int e = base + i * 256 + t;
        if (e < NE) {
            atomicAdd(&cp[ep[e] >> 10], 1);
            atomicAdd(&cc[ec[e] >> 8], 1);
        }
    }
    __syncthreads();
    if (t < PBK) { bp_[t] = atomicAdd(&PCUR[t * 16], cp[t]); cp[t] = 0; }
    if (t < CBK) { bc_[t] = atomicAdd(&CCUR[t * 16], cc[t]); cc[t] = 0; }
    __syncthreads();
    #pragma unroll
    for (int i = 0; i < CHUNK / 256; ++i) {
        int e = base + i * 256 + t;
        if (e < NE) {
            unsigned p = (unsigned)ep[e];
            unsigned c = (unsigned)ec[e];
            unsigned wb = __float_as_uint(ew[e]);
            int b1 = p >> 10;
            int pos = bp_[b1] + atomicAdd(&cp[b1], 1);
            Ap[pos] = make_uint2(((p & 1023u) << 15) | c, wb);
            int b2 = c >> 8;
            int pos2 = bc_[b2] + atomicAdd(&cc[b2], 1);
            Ac[pos2] = make_uint2(((c & 255u) << 17) | p, wb);
        }
    }
}

// ---------------- pass B: within-bucket counting sort + per-row CSR ----------------
template<int LOCALS, int SHIFT, unsigned NMASK>
__global__ __launch_bounds__(256) void bsort_kernel(
    const uint2* __restrict__ A, const int* __restrict__ OFF,
    int2* __restrict__ S, int* __restrict__ rowoff, int nrows_total, int nbins)
{
    __shared__ int cnt[LOCALS];
    __shared__ int tsum[256];
    constexpr int NL = LOCALS / 256;
    int t = threadIdx.x;
    int b = blockIdx.x;
    int s0 = OFF[b], e0 = OFF[b + 1];
    #pragma unroll
    for (int k = 0; k < NL; ++k) cnt[t * NL + k] = 0;
    __syncthreads();
    for (int j = s0 + t; j < e0; j += 256)
        atomicAdd(&cnt[A[j].x >> SHIFT], 1);
    __syncthreads();
    int pre[NL];
    int run = 0;
    #pragma unroll
    for (int k = 0; k < NL; ++k) { pre[k] = run; run += cnt[t * NL + k]; }
    tsum[t] = run;
    __syncthreads();
    for (int off = 1; off < 256; off <<= 1) {
        int a = (t >= off) ? tsum[t - off] : 0;
        __syncthreads();
        tsum[t] += a;
        __syncthreads();
    }
    int excl = t ? tsum[t - 1] : 0;
    #pragma unroll
    for (int k = 0; k < NL; ++k) cnt[t * NL + k] = excl + pre[k];
    __syncthreads();
    int rowbase = b * LOCALS;
    #pragma unroll
    for (int k = 0; k < NL; ++k) {
        int r = t * NL + k;
        if (rowbase + r < nrows_total) rowoff[rowbase + r] = s0 + cnt[r];
    }
    if (b == nbins - 1 && t == 0) rowoff[nrows_total] = e0;
    __syncthreads();
    for (int j = s0 + t; j < e0; j += 256) {
        uint2 v = A[j];
        int loc = (int)(v.x >> SHIFT);
        int pos = s0 + atomicAdd(&cnt[loc], 1);
        S[pos] = make_int2((int)(v.x & NMASK), (int)v.y);
    }
}

// ---------------- aggregate: wave per row, bf16 gather, bf16 msg out ----------------
__global__ __launch_bounds__(256) void agg_kernel(
    const int2* __restrict__ sorted, const int* __restrict__ off,
    const unsigned short* __restrict__ nbremb_bf, unsigned short* __restrict__ msg_bf)
{
    int wave = threadIdx.x >> 6;
    int lane = threadIdx.x & 63;
    int row = blockIdx.x * 4 + wave;   // grid sized exactly
    int start = off[row];
    int end   = off[row + 1];
    float acc0 = 0.f, acc1 = 0.f, deg = 0.f;
    for (int j = start; j < end; ++j) {
        int2 v = sorted[j];
        float w = __int_as_float(v.y);
        unsigned pk = *(const unsigned*)(nbremb_bf + (size_t)v.x * DIM + 2 * lane);
        deg  += w;
        acc0 += w * bf2f(pk & 0xFFFFu);
        acc1 += w * bf2f(pk >> 16);
    }
    float inv = 1.0f / (deg + 1e-8f);
    unsigned o = f2bf(acc0 * inv) | (f2bf(acc1 * inv) << 16);
    *(unsigned*)(msg_bf + (size_t)row * DIM + 2 * lane) = o;
}

// ---------------- MFMA MLP: swapped-operand, wave per 16 rows ----------------
// layer1: h^T[j][row] = sum_k w1^T[j][k] x^T[k][row]  via mfma(A=w1pk, B=x)
// lane holds h[row = lane&15][j = mt*16 + (lane>>4)*4 + r]
#define HP 136   // hs row pitch in bf16 (272 B: 16B-aligned reads, spread banks)
__global__ __launch_bounds__(256) void mlp_mfma_kernel(
    const unsigned short* __restrict__ embbf, const unsigned short* __restrict__ msgbf,
    const unsigned short* __restrict__ w1pk, const unsigned short* __restrict__ w2pk,
    const float* __restrict__ b1, const float* __restrict__ g1, const float* __restrict__ be1,
    const float* __restrict__ b2, const float* __restrict__ g2, const float* __restrict__ be2,
    float* __restrict__ out, int nrows)
{
    __shared__ __align__(16) unsigned short hs_all[4][16 * HP];
    int t = threadIdx.x;
    int wave = t >> 6, lane = t & 63;
    int tile = blockIdx.x * 4 + wave;
    if (tile * 16 >= nrows) return;          // padding waves only; no barriers used
    int r16 = lane & 15;
    int hi  = lane >> 4;
    int row = tile * 16 + r16;
    unsigned short* hs = hs_all[wave];

    // ---- layer 1: 8 mt x 8 ks MFMAs ----
    f32x4 acc[8];
    #pragma unroll
    for (int mt = 0; mt < 8; ++mt) {
        float4 bb = *(const float4*)&b1[mt * 16 + hi * 4];
        acc[mt] = (f32x4){bb.x, bb.y, bb.z, bb.w};
    }
    const unsigned short* x0 = embbf + (size_t)row * DIM;
    const unsigned short* x1 = msgbf + (size_t)row * DIM;
    #pragma unroll
    for (int ks = 0; ks < 8; ++ks) {
        const unsigned short* xs = (ks < 4) ? (x0 + ks * 32 + hi * 8)
                                            : (x1 + (ks - 4) * 32 + hi * 8);
        short8v bfrag = *(const short8v*)xs;
        #pragma unroll
        for (int mt = 0; mt < 8; ++mt) {
            short8v afrag = *(const short8v*)(w1pk + (((mt * 8 + ks) * 64 + lane) << 3));
            acc[mt] = __builtin_amdgcn_mfma_f32_16x16x32_bf16(afrag, bfrag, acc[mt], 0, 0, 0);
        }
    }

    // ---- LN1 + ReLU -> hs (bf16) ----
    float s = 0.f, q = 0.f;
    #pragma unroll
    for (int mt = 0; mt < 8; ++mt) {
        #pragma unroll
        for (int r = 0; r < 4; ++r) { float v = acc[mt][r]; s += v; q += v * v; }
    }
    s += __shfl_xor(s, 16); s += __shfl_xor(s, 32);
    q += __shfl_xor(q, 16); q += __shfl_xor(q, 32);
    float mu = s * (1.0f / 128.0f);
    float var = q * (1.0f / 128.0f) - mu * mu;
    float rstd = rsqrtf(var + 1e-5f);
    #pragma unroll
    for (int mt = 0; mt < 8; ++mt) {
        float4 gg = *(const float4*)&g1[mt * 16 + hi * 4];
        float4 bb = *(const float4*)&be1[mt * 16 + hi * 4];
        float h0 = fmaxf((acc[mt][0] - mu) * rstd * gg.x + bb.x, 0.f);
        float h1 = fmaxf((acc[mt][1] - mu) * rstd * gg.y + bb.y, 0.f);
        float h2 = fmaxf((acc[mt][2] - mu) * rstd * gg.z + bb.z, 0.f);
        float h3 = fmaxf((acc[mt][3] - mu) * rstd * gg.w + bb.w, 0.f);
        uint2 pk = make_uint2(f2bf(h0) | (f2bf(h1) << 16), f2bf(h2) | (f2bf(h3) << 16));
        *(uint2*)&hs[r16 * HP + mt * 16 + hi * 4] = pk;
    }

    // ---- layer 2: 4 mt x 4 ks MFMAs (B-frag = contiguous hs row reads) ----
    f32x4 acc2[4];
    #pragma unroll
    for (int mt = 0; mt < 4; ++mt) {
        float4 bb = *(const float4*)&b2[mt * 16 + hi * 4];
        acc2[mt] = (f32x4){bb.x, bb.y, bb.z, bb.w};
    }
    #pragma unroll
    for (int ks = 0; ks < 4; ++ks) {
        short8v bfrag = *(const short8v*)&hs[r16 * HP + ks * 32 + hi * 8];
        #pragma unroll
        for (int mt = 0; mt < 4; ++mt) {
            short8v afrag = *(const short8v*)(w2pk + (((mt * 4 + ks) * 64 + lane) << 3));
            acc2[mt] = __builtin_amdgcn_mfma_f32_16x16x32_bf16(afrag, bfrag, acc2[mt], 0, 0, 0);
        }
    }

    // ---- LN2 -> out ----
    float s2 = 0.f, q2 = 0.f;
    #pragma unroll
    for (int mt = 0; mt < 4; ++mt) {
        #pragma unroll
        for (int r = 0; r < 4; ++r) { float v = acc2[mt][r]; s2 += v; q2 += v * v; }
    }
    s2 += __shfl_xor(s2, 16); s2 += __shfl_xor(s2, 32);
    q2 += __shfl_xor(q2, 16); q2 += __shfl_xor(q2, 32);
    float mu2 = s2 * (1.0f / 64.0f);
    float var2 = q2 * (1.0f / 64.0f) - mu2 * mu2;
    float rstd2 = rsqrtf(var2 + 1e-5f);
    #pragma unroll
    for (int mt = 0; mt < 4; ++mt) {
        float4 gg = *(const float4*)&g2[mt * 16 + hi * 4];
        float4 bb = *(const float4*)&be2[mt * 16 + hi * 4];
        float4 o;
        o.x = (acc2[mt][0] - mu2) * rstd2 * gg.x + bb.x;
        o.y = (acc2[mt][1] - mu2) * rstd2 * gg.y + bb.y;
        o.z = (acc2[mt][2] - mu2) * rstd2 * gg.z + bb.z;
        o.w = (acc2[mt][3] - mu2) * rstd2 * gg.w + bb.w;
        *(float4*)&out[(size_t)row * OUTD + mt * 16 + hi * 4] = o;
    }
}

extern "C" void kernel_launch(void* const* d_in, const int* in_sizes, int n_in,
                              void* d_out, int out_size, void* d_ws, size_t ws_size,
                              hipStream_t stream) {
    const int*   ep   = (const int*)d_in[0];
    const int*   ec   = (const int*)d_in[1];
    const float* ew   = (const float*)d_in[2];
    const float* pemb = (const float*)d_in[3];
    const float* cemb = (const float*)d_in[4];
    const float* w1p  = (const float*)d_in[5];
    const float* b1p  = (const float*)d_in[6];
    const float* g1p  = (const float*)d_in[7];
    const float* be1p = (const float*)d_in[8];
    const float* w2p  = (const float*)d_in[9];
    const float* b2p  = (const float*)d_in[10];
    const float* g2p  = (const float*)d_in[11];
    const float* be2p = (const float*)d_in[12];
    const float* w1c  = (const float*)d_in[13];
    const float* b1c  = (const float*)d_in[14];
    const float* g1c  = (const float*)d_in[15];
    const float* be1c = (const float*)d_in[16];
    const float* w2c  = (const float*)d_in[17];
    const float* b2c  = (const float*)d_in[18];
    const float* g2c  = (const float*)d_in[19];
    const float* be2c = (const float*)d_in[20];

    // ---- meta workspace (ints) ----
    int* wsi  = (int*)d_ws;
    int* PH   = wsi;               // [98*16]  zeroed every call
    int* CH   = PH + 1568;         // [79*16]  zeroed every call
    int* PCUR = CH + 1264;         // [98*16]  (written by bscan)
    int* CCUR = PCUR + 1568;       // [79*16]
    int* POFF = CCUR + 1264;       // [100]
    int* COFF = POFF + 100;        // [84]
    int* rowoff_p = COFF + 84;         // [100004]
    int* rowoff_c = rowoff_p + 100004; // [20004]
    const int zero_ints = 1568 + 1264;                                      // 2832
    const int meta_ints = 2832 + 1568 + 1264 + 100 + 84 + 100004 + 20004;   // 125856

    // ---- big regions (stream-ordered lifetimes; aliases noted) ----
    char* big = (char*)(wsi + meta_ints);
    uint2* Ap = (uint2*)big;                             // 16 MB  (part out, bsort_p in)
    int2*  Sp = (int2*)(big + 16000000);                 // 16 MB  (bsort_p out, agg_p in)
    char*  zoneC = big + 32000000;                       // 30.72 MB zone
    uint2* Ac = (uint2*)zoneC;                           //   16 MB (part out, bsort_c in)
    int2*  Sc = (int2*)Ap;                               //   aliases Ap (dead after bsort_p)
    unsigned short* pmsgb = (unsigned short*)zoneC;                   // 25.6 MB (after bsort_c)
    unsigned short* cmsgb = (unsigned short*)(zoneC + 25600000);      // 5.12 MB
    unsigned short* pembbf = (unsigned short*)(zoneC + 30720000);     // 25.6 MB
    unsigned short* cembbf = pembbf + (size_t)NP * DIM;               // 5.12 MB
    unsigned short* w1pk_p = cembbf + (size_t)NC * DIM;  // 64 KB
    unsigned short* w2pk_p = w1pk_p + 32768;             // 16 KB
    unsigned short* w1pk_c = w2pk_p + 8192;              // 64 KB
    unsigned short* w2pk_c = w1pk_c + 32768;             // 16 KB

    zero4_kernel<<<3, 256, 0, stream>>>((float4*)wsi, (size_t)zero_ints / 4);

    // bf16 conversions + weight prepack (independent of edge pipeline)
    conv_kernel<<<2048, 256, 0, stream>>>((const float4*)pemb, (uint2*)pembbf,
                                          (size_t)NP * DIM / 4);
    conv_kernel<<<640, 256, 0, stream>>>((const float4*)cemb, (uint2*)cembbf,
                                         (size_t)NC * DIM / 4);
    pack_kernel<<<40, 256, 0, stream>>>(w1p, w2p, w1c, w2c,
                                        w1pk_p, w2pk_p, w1pk_c, w2pk_c);

    bhist_kernel<<<256, 256, 0, stream>>>(ep, ec, PH, CH);
    bscan_kernel<<<1, 256, 0, stream>>>(PH, CH, POFF, COFF, PCUR, CCUR);

    int pblocks = (NE + CHUNK - 1) / CHUNK;   // 489
    part_kernel<<<pblocks, 256, 0, stream>>>(ep, ec, ew, PCUR, CCUR, Ap, Ac);

    bsort_kernel<1024, 15, 0x7FFFu><<<PBK, 256, 0, stream>>>(Ap, POFF, Sp, rowoff_p, NP, PBK);
    bsort_kernel<256, 17, 0x1FFFFu><<<CBK, 256, 0, stream>>>(Ac, COFF, Sc, rowoff_c, NC, CBK);

    agg_kernel<<<NP / 4, 256, 0, stream>>>(Sp, rowoff_p, cembbf, pmsgb);
    agg_kernel<<<NC / 4, 256, 0, stream>>>(Sc, rowoff_c, pembbf, cmsgb);

    float* out_p = (float*)d_out;             // [NP, 64]
    float* out_c = out_p + (size_t)NP * OUTD; // [NC, 64]

    mlp_mfma_kernel<<<(NP / 16 + 3) / 4, 256, 0, stream>>>(
        pembbf, pmsgb, w1pk_p, w2pk_p,
        b1p, g1p, be1p, b2p, g2p, be2p, out_p, NP);
    mlp_mfma_kernel<<<(NC / 16 + 3) / 4, 256, 0, stream>>>(
        cembbf, cmsgb, w1pk_c, w2pk_c,
        b1c, g1c, be1c, b2c, g2c, be2c, out_c, NC);
}

// Round 10
// 379.728 us; speedup vs baseline: 14.7163x; 1.5761x over previous
//
#include <hip/hip_runtime.h>
#include <cstddef>

#define NP 100000
#define NC 20000
#define NE 2000000
#define DIM 128
#define HID 128
#define OUTD 64

#define PBK 98      // ceil(NP/1024) buckets of 1024 providers
#define CBK 79      // ceil(NC/256)  buckets of 256 codes
#define CHUNK 4096  // edges per part-block

typedef __attribute__((ext_vector_type(8))) short short8v;
typedef __attribute__((ext_vector_type(4))) float f32x4;

__device__ __forceinline__ unsigned f2bf(float f) {
    unsigned u = __float_as_uint(f);
    return (u + 0x7FFFu + ((u >> 16) & 1u)) >> 16;   // RNE
}
__device__ __forceinline__ float bf2f(unsigned s) {
    return __uint_as_float(s << 16);
}

// ---------------- zero (bucket histograms only) ----------------
__global__ void zero4_kernel(float4* p, size_t n4) {
    size_t i = blockIdx.x * (size_t)blockDim.x + threadIdx.x;
    size_t stride = (size_t)gridDim.x * blockDim.x;
    float4 z = make_float4(0.f, 0.f, 0.f, 0.f);
    for (; i < n4; i += stride) p[i] = z;
}

// ---------------- f32 -> bf16 conversion ----------------
__global__ void conv_kernel(const float4* __restrict__ in, uint2* __restrict__ outp, size_t n4) {
    size_t i = blockIdx.x * (size_t)blockDim.x + threadIdx.x;
    size_t st = (size_t)gridDim.x * blockDim.x;
    for (; i < n4; i += st) {
        float4 v = in[i];
        outp[i] = make_uint2(f2bf(v.x) | (f2bf(v.y) << 16),
                             f2bf(v.z) | (f2bf(v.w) << 16));
    }
}

// ---------------- prepack weights into MFMA A-fragment order ----------------
__device__ __forceinline__ void pack_one(const float* __restrict__ w, unsigned short* __restrict__ dst,
                                         int M, int KT, int idx) {
    int lane = idx & 63;
    int rest = idx >> 6;
    int ks = rest % KT;
    int mt = rest / KT;
    int m  = mt * 16 + (lane & 15);
    int kb = ks * 32 + ((lane >> 4) << 3);
    uint4 r;
    r.x = f2bf(w[(kb + 0) * M + m]) | (f2bf(w[(kb + 1) * M + m]) << 16);
    r.y = f2bf(w[(kb + 2) * M + m]) | (f2bf(w[(kb + 3) * M + m]) << 16);
    r.z = f2bf(w[(kb + 4) * M + m]) | (f2bf(w[(kb + 5) * M + m]) << 16);
    r.w = f2bf(w[(kb + 6) * M + m]) | (f2bf(w[(kb + 7) * M + m]) << 16);
    *(uint4*)(dst + (size_t)idx * 8) = r;
}
__global__ __launch_bounds__(256) void pack_kernel(
    const float* __restrict__ w1p, const float* __restrict__ w2p,
    const float* __restrict__ w1c, const float* __restrict__ w2c,
    unsigned short* __restrict__ d1p, unsigned short* __restrict__ d2p,
    unsigned short* __restrict__ d1c, unsigned short* __restrict__ d2c) {
    int idx = blockIdx.x * 256 + threadIdx.x;     // 0..10239
    if (idx < 4096)       pack_one(w1p, d1p, 128, 8, idx);
    else if (idx < 5120)  pack_one(w2p, d2p, 64, 4, idx - 4096);
    else if (idx < 9216)  pack_one(w1c, d1c, 128, 8, idx - 5120);
    else if (idx < 10240) pack_one(w2c, d2c, 64, 4, idx - 9216);
}

// ---------------- bucket histogram ----------------
__global__ __launch_bounds__(256) void bhist_kernel(
    const int* __restrict__ ep, const int* __restrict__ ec,
    int* __restrict__ PH, int* __restrict__ CH)
{
    __shared__ int hp[PBK];
    __shared__ int hc[CBK];
    int t = threadIdx.x;
    if (t < PBK) hp[t] = 0;
    if (t < CBK) hc[t] = 0;
    __syncthreads();
    for (int e = blockIdx.x * 256 + t; e < NE; e += 256 * 256) {
        atomicAdd(&hp[ep[e] >> 10], 1);
        atomicAdd(&hc[ec[e] >> 8], 1);
    }
    __syncthreads();
    if (t < PBK) atomicAdd(&PH[t * 16], hp[t]);
    if (t < CBK) atomicAdd(&CH[t * 16], hc[t]);
}

// ---------------- bucket scans ----------------
__global__ __launch_bounds__(256) void bscan_kernel(
    const int* __restrict__ PH, const int* __restrict__ CH,
    int* __restrict__ POFF, int* __restrict__ COFF,
    int* __restrict__ PCUR, int* __restrict__ CCUR)
{
    __shared__ int s[256];
    int t = threadIdx.x;
    s[t] = (t < PBK) ? PH[t * 16] : 0;
    __syncthreads();
    for (int off = 1; off < 256; off <<= 1) {
        int a = (t >= off) ? s[t - off] : 0;
        __syncthreads();
        s[t] += a;
        __syncthreads();
    }
    int excl = t ? s[t - 1] : 0;
    if (t < PBK) { POFF[t] = excl; PCUR[t * 16] = excl; }
    if (t == 0) POFF[PBK] = NE;
    __syncthreads();
    s[t] = (t < CBK) ? CH[t * 16] : 0;
    __syncthreads();
    for (int off = 1; off < 256; off <<= 1) {
        int a = (t >= off) ? s[t - off] : 0;
        __syncthreads();
        s[t] += a;
        __syncthreads();
    }
    excl = t ? s[t - 1] : 0;
    if (t < CBK) { COFF[t] = excl; CCUR[t * 16] = excl; }
    if (t == 0) COFF[CBK] = NE;
}

// ---------------- pass A: partition into buckets ----------------
// P record: ((p&1023)<<15)|c ; C record: ((c&255)<<17)|p ; .y = weight bits
__global__ __launch_bounds__(256) void part_kernel(
    const int* __restrict__ ep, const int* __restrict__ ec, const float* __restrict__ ew,
    int* __restrict__ PCUR, int* __restrict__ CCUR,
    uint2* __restrict__ Ap, uint2* __restrict__ Ac)
{
    __shared__ int cp[PBK], bp_[PBK], cc[CBK], bc_[CBK];
    int t = threadIdx.x;
    int base = blockIdx.x * CHUNK;
    if (t < PBK) cp[t] = 0;
    if (t < CBK) cc[t] = 0;
    __syncthreads();
    #pragma unroll
    for (int i = 0; i < CHUNK / 256; ++i) {
        int e = base + i * 256 + t;
        if (e < NE) {
            atomicAdd(&cp[ep[e] >> 10], 1);
            atomicAdd(&cc[ec[e] >> 8], 1);
        }
    }
    __syncthreads();
    if (t < PBK) { bp_[t] = atomicAdd(&PCUR[t * 16], cp[t]); cp[t] = 0; }
    if (t < CBK) { bc_[t] = atomicAdd(&CCUR[t * 16], cc[t]); cc[t] = 0; }
    __syncthreads();
    #pragma unroll
    for (int i = 0; i < CHUNK / 256; ++i) {
        int e = base + i * 256 + t;
        if (e < NE) {
            unsigned p = (unsigned)ep[e];
            unsigned c = (unsigned)ec[e];
            unsigned wb = __float_as_uint(ew[e]);
            int b1 = p >> 10;
            int pos = bp_[b1] + atomicAdd(&cp[b1], 1);
            Ap[pos] = make_uint2(((p & 1023u) << 15) | c, wb);
            int b2 = c >> 8;
            int pos2 = bc_[b2] + atomicAdd(&cc[b2], 1);
            Ac[pos2] = make_uint2(((c & 255u) << 17) | p, wb);
        }
    }
}

// ---------------- pass B: within-bucket counting sort + per-row CSR ----------------
template<int LOCALS, int SHIFT, unsigned NMASK>
__global__ __launch_bounds__(256) void bsort_kernel(
    const uint2* __restrict__ A, const int* __restrict__ OFF,
    int2* __restrict__ S, int* __restrict__ rowoff, int nrows_total, int nbins)
{
    __shared__ int cnt[LOCALS];
    __shared__ int tsum[256];
    constexpr int NL = LOCALS / 256;
    int t = threadIdx.x;
    int b = blockIdx.x;
    int s0 = OFF[b], e0 = OFF[b + 1];
    #pragma unroll
    for (int k = 0; k < NL; ++k) cnt[t * NL + k] = 0;
    __syncthreads();
    for (int j = s0 + t; j < e0; j += 256)
        atomicAdd(&cnt[A[j].x >> SHIFT], 1);
    __syncthreads();
    int pre[NL];
    int run = 0;
    #pragma unroll
    for (int k = 0; k < NL; ++k) { pre[k] = run; run += cnt[t * NL + k]; }
    tsum[t] = run;
    __syncthreads();
    for (int off = 1; off < 256; off <<= 1) {
        int a = (t >= off) ? tsum[t - off] : 0;
        __syncthreads();
        tsum[t] += a;
        __syncthreads();
    }
    int excl = t ? tsum[t - 1] : 0;
    #pragma unroll
    for (int k = 0; k < NL; ++k) cnt[t * NL + k] = excl + pre[k];
    __syncthreads();
    int rowbase = b * LOCALS;
    #pragma unroll
    for (int k = 0; k < NL; ++k) {
        int r = t * NL + k;
        if (rowbase + r < nrows_total) rowoff[rowbase + r] = s0 + cnt[r];
    }
    if (b == nbins - 1 && t == 0) rowoff[nrows_total] = e0;
    __syncthreads();   // rowoff reads of cnt complete before scatter mutates cnt
    for (int j = s0 + t; j < e0; j += 256) {
        uint2 v = A[j];
        int loc = (int)(v.x >> SHIFT);
        int pos = s0 + atomicAdd(&cnt[loc], 1);
        S[pos] = make_int2((int)(v.x & NMASK), (int)v.y);
    }
}

// ---------------- aggregate: wave per row, bf16 gather, unroll x4 ----------------
// Fixed-point int32 accumulation (scale 2^21): integer sums are order-invariant,
// so the racy storage order upstream cannot change the output bit pattern
// between calls. Bounds: |emb| <= ~0.02, weighted degree <= ~300 ->
// |iacc| < 2^24, |ideg| < 2^30; per-term quantization 2^-21 (below bf16 LSB).
__global__ __launch_bounds__(256) void agg_kernel(
    const int2* __restrict__ sorted, const int* __restrict__ off,
    const unsigned short* __restrict__ nbremb_bf, unsigned short* __restrict__ msg_bf)
{
    const float SCL  = 2097152.0f;          // 2^21
    const float ISCL = 1.0f / 2097152.0f;
    int wave = threadIdx.x >> 6;
    int lane = threadIdx.x & 63;
    int row = blockIdx.x * 4 + wave;   // grid sized exactly
    int start = off[row];
    int end   = off[row + 1];
    int iacc0 = 0, iacc1 = 0, ideg = 0;
    int j = start;
    for (; j + 4 <= end; j += 4) {
        int2 v0 = sorted[j];
        int2 v1 = sorted[j + 1];
        int2 v2 = sorted[j + 2];
        int2 v3 = sorted[j + 3];
        unsigned pk0 = *(const unsigned*)(nbremb_bf + (size_t)v0.x * DIM + 2 * lane);
        unsigned pk1 = *(const unsigned*)(nbremb_bf + (size_t)v1.x * DIM + 2 * lane);
        unsigned pk2 = *(const unsigned*)(nbremb_bf + (size_t)v2.x * DIM + 2 * lane);
        unsigned pk3 = *(const unsigned*)(nbremb_bf + (size_t)v3.x * DIM + 2 * lane);
        float w0 = __int_as_float(v0.y), w1 = __int_as_float(v1.y);
        float w2 = __int_as_float(v2.y), w3 = __int_as_float(v3.y);
        ideg  += (int)(w0 * SCL) + (int)(w1 * SCL) + (int)(w2 * SCL) + (int)(w3 * SCL);
        iacc0 += (int)(w0 * bf2f(pk0 & 0xFFFFu) * SCL) + (int)(w1 * bf2f(pk1 & 0xFFFFu) * SCL)
               + (int)(w2 * bf2f(pk2 & 0xFFFFu) * SCL) + (int)(w3 * bf2f(pk3 & 0xFFFFu) * SCL);
        iacc1 += (int)(w0 * bf2f(pk0 >> 16) * SCL) + (int)(w1 * bf2f(pk1 >> 16) * SCL)
               + (int)(w2 * bf2f(pk2 >> 16) * SCL) + (int)(w3 * bf2f(pk3 >> 16) * SCL);
    }
    for (; j < end; ++j) {
        int2 v = sorted[j];
        float w = __int_as_float(v.y);
        unsigned pk = *(const unsigned*)(nbremb_bf + (size_t)v.x * DIM + 2 * lane);
        ideg  += (int)(w * SCL);
        iacc0 += (int)(w * bf2f(pk & 0xFFFFu) * SCL);
        iacc1 += (int)(w * bf2f(pk >> 16) * SCL);
    }
    float deg = (float)ideg * ISCL;
    float inv = 1.0f / (deg + 1e-8f);
    float a0 = (float)iacc0 * ISCL;
    float a1 = (float)iacc1 * ISCL;
    unsigned o = f2bf(a0 * inv) | (f2bf(a1 * inv) << 16);
    *(unsigned*)(msg_bf + (size_t)row * DIM + 2 * lane) = o;
}

// ---------------- MFMA MLP: swapped-operand, wave per 16 rows ----------------
#define HP 136   // hs row pitch in bf16
__global__ __launch_bounds__(256) void mlp_mfma_kernel(
    const unsigned short* __restrict__ embbf, const unsigned short* __restrict__ msgbf,
    const unsigned short* __restrict__ w1pk, const unsigned short* __restrict__ w2pk,
    const float* __restrict__ b1, const float* __restrict__ g1, const float* __restrict__ be1,
    const float* __restrict__ b2, const float* __restrict__ g2, const float* __restrict__ be2,
    float* __restrict__ out, int nrows)
{
    __shared__ __align__(16) unsigned short hs_all[4][16 * HP];
    int t = threadIdx.x;
    int wave = t >> 6, lane = t & 63;
    int tile = blockIdx.x * 4 + wave;
    if (tile * 16 >= nrows) return;          // padding waves only; no barriers used
    int r16 = lane & 15;
    int hi  = lane >> 4;
    int row = tile * 16 + r16;
    unsigned short* hs = hs_all[wave];

    // ---- layer 1: 8 mt x 8 ks MFMAs ----
    f32x4 acc[8];
    #pragma unroll
    for (int mt = 0; mt < 8; ++mt) {
        float4 bb = *(const float4*)&b1[mt * 16 + hi * 4];
        acc[mt] = (f32x4){bb.x, bb.y, bb.z, bb.w};
    }
    const unsigned short* x0 = embbf + (size_t)row * DIM;
    const unsigned short* x1 = msgbf + (size_t)row * DIM;
    #pragma unroll
    for (int ks = 0; ks < 8; ++ks) {
        const unsigned short* xs = (ks < 4) ? (x0 + ks * 32 + hi * 8)
                                            : (x1 + (ks - 4) * 32 + hi * 8);
        short8v bfrag = *(const short8v*)xs;
        #pragma unroll
        for (int mt = 0; mt < 8; ++mt) {
            short8v afrag = *(const short8v*)(w1pk + (((mt * 8 + ks) * 64 + lane) << 3));
            acc[mt] = __builtin_amdgcn_mfma_f32_16x16x32_bf16(afrag, bfrag, acc[mt], 0, 0, 0);
        }
    }

    // ---- LN1 + ReLU -> hs (bf16) ----
    float s = 0.f, q = 0.f;
    #pragma unroll
    for (int mt = 0; mt < 8; ++mt) {
        #pragma unroll
        for (int r = 0; r < 4; ++r) { float v = acc[mt][r]; s += v; q += v * v; }
    }
    s += __shfl_xor(s, 16); s += __shfl_xor(s, 32);
    q += __shfl_xor(q, 16); q += __shfl_xor(q, 32);
    float mu = s * (1.0f / 128.0f);
    float var = q * (1.0f / 128.0f) - mu * mu;
    float rstd = rsqrtf(var + 1e-5f);
    #pragma unroll
    for (int mt = 0; mt < 8; ++mt) {
        float4 gg = *(const float4*)&g1[mt * 16 + hi * 4];
        float4 bb = *(const float4*)&be1[mt * 16 + hi * 4];
        float h0 = fmaxf((acc[mt][0] - mu) * rstd * gg.x + bb.x, 0.f);
        float h1 = fmaxf((acc[mt][1] - mu) * rstd * gg.y + bb.y, 0.f);
        float h2 = fmaxf((acc[mt][2] - mu) * rstd * gg.z + bb.z, 0.f);
        float h3 = fmaxf((acc[mt][3] - mu) * rstd * gg.w + bb.w, 0.f);
        uint2 pk = make_uint2(f2bf(h0) | (f2bf(h1) << 16), f2bf(h2) | (f2bf(h3) << 16));
        *(uint2*)&hs[r16 * HP + mt * 16 + hi * 4] = pk;
    }

    // ---- layer 2: 4 mt x 4 ks MFMAs ----
    f32x4 acc2[4];
    #pragma unroll
    for (int mt = 0; mt < 4; ++mt) {
        float4 bb = *(const float4*)&b2[mt * 16 + hi * 4];
        acc2[mt] = (f32x4){bb.x, bb.y, bb.z, bb.w};
    }
    #pragma unroll
    for (int ks = 0; ks < 4; ++ks) {
        short8v bfrag = *(const short8v*)&hs[r16 * HP + ks * 32 + hi * 8];
        #pragma unroll
        for (int mt = 0; mt < 4; ++mt) {
            short8v afrag = *(const short8v*)(w2pk + (((mt * 4 + ks) * 64 + lane) << 3));
            acc2[mt] = __builtin_amdgcn_mfma_f32_16x16x32_bf16(afrag, bfrag, acc2[mt], 0, 0, 0);
        }
    }

    // ---- LN2 -> out ----
    float s2 = 0.f, q2 = 0.f;
    #pragma unroll
    for (int mt = 0; mt < 4; ++mt) {
        #pragma unroll
        for (int r = 0; r < 4; ++r) { float v = acc2[mt][r]; s2 += v; q2 += v * v; }
    }
    s2 += __shfl_xor(s2, 16); s2 += __shfl_xor(s2, 32);
    q2 += __shfl_xor(q2, 16); q2 += __shfl_xor(q2, 32);
    float mu2 = s2 * (1.0f / 64.0f);
    float var2 = q2 * (1.0f / 64.0f) - mu2 * mu2;
    float rstd2 = rsqrtf(var2 + 1e-5f);
    #pragma unroll
    for (int mt = 0; mt < 4; ++mt) {
        float4 gg = *(const float4*)&g2[mt * 16 + hi * 4];
        float4 bb = *(const float4*)&be2[mt * 16 + hi * 4];
        float4 o;
        o.x = (acc2[mt][0] - mu2) * rstd2 * gg.x + bb.x;
        o.y = (acc2[mt][1] - mu2) * rstd2 * gg.y + bb.y;
        o.z = (acc2[mt][2] - mu2) * rstd2 * gg.z + bb.z;
        o.w = (acc2[mt][3] - mu2) * rstd2 * gg.w + bb.w;
        *(float4*)&out[(size_t)row * OUTD + mt * 16 + hi * 4] = o;
    }
}

extern "C" void kernel_launch(void* const* d_in, const int* in_sizes, int n_in,
                              void* d_out, int out_size, void* d_ws, size_t ws_size,
                              hipStream_t stream) {
    const int*   ep   = (const int*)d_in[0];
    const int*   ec   = (const int*)d_in[1];
    const float* ew   = (const float*)d_in[2];
    const float* pemb = (const float*)d_in[3];
    const float* cemb = (const float*)d_in[4];
    const float* w1p  = (const float*)d_in[5];
    const float* b1p  = (const float*)d_in[6];
    const float* g1p  = (const float*)d_in[7];
    const float* be1p = (const float*)d_in[8];
    const float* w2p  = (const float*)d_in[9];
    const float* b2p  = (const float*)d_in[10];
    const float* g2p  = (const float*)d_in[11];
    const float* be2p = (const float*)d_in[12];
    const float* w1c  = (const float*)d_in[13];
    const float* b1c  = (const float*)d_in[14];
    const float* g1c  = (const float*)d_in[15];
    const float* be1c = (const float*)d_in[16];
    const float* w2c  = (const float*)d_in[17];
    const float* b2c  = (const float*)d_in[18];
    const float* g2c  = (const float*)d_in[19];
    const float* be2c = (const float*)d_in[20];

    // ---- meta workspace (ints) ----
    int* wsi  = (int*)d_ws;
    int* PH   = wsi;               // [98*16]  zeroed every call
    int* CH   = PH + 1568;         // [79*16]  zeroed every call
    int* PCUR = CH + 1264;         // [98*16]  (written by bscan)
    int* CCUR = PCUR + 1568;       // [79*16]
    int* POFF = CCUR + 1264;       // [100]
    int* COFF = POFF + 100;        // [84]
    int* rowoff_p = COFF + 84;         // [100004]
    int* rowoff_c = rowoff_p + 100004; // [20004]
    const int zero_ints = 1568 + 1264;                                      // 2832
    const int meta_ints = 2832 + 1568 + 1264 + 100 + 84 + 100004 + 20004;   // 125856

    // ---- big regions (stream-ordered lifetimes; aliases noted) ----
    char* big = (char*)(wsi + meta_ints);
    uint2* Ap = (uint2*)big;                             // 16 MB  (part out, bsort_p in)
    int2*  Sp = (int2*)(big + 16000000);                 // 16 MB  (bsort_p out, agg_p in)
    char*  zoneC = big + 32000000;                       // 30.72 MB zone
    uint2* Ac = (uint2*)zoneC;                           //   16 MB (part out, bsort_c in)
    int2*  Sc = (int2*)Ap;                               //   aliases Ap (dead after bsort_p)
    unsigned short* pmsgb = (unsigned short*)zoneC;                   // 25.6 MB (after bsort_c)
    unsigned short* cmsgb = (unsigned short*)(zoneC + 25600000);      // 5.12 MB
    unsigned short* pembbf = (unsigned short*)(zoneC + 30720000);     // 25.6 MB
    unsigned short* cembbf = pembbf + (size_t)NP * DIM;               // 5.12 MB
    unsigned short* w1pk_p = cembbf + (size_t)NC * DIM;  // 64 KB
    unsigned short* w2pk_p = w1pk_p + 32768;             // 16 KB
    unsigned short* w1pk_c = w2pk_p + 8192;              // 64 KB
    unsigned short* w2pk_c = w1pk_c + 32768;             // 16 KB

    zero4_kernel<<<3, 256, 0, stream>>>((float4*)wsi, (size_t)zero_ints / 4);

    // bf16 conversions + weight prepack (independent of edge pipeline)
    conv_kernel<<<2048, 256, 0, stream>>>((const float4*)pemb, (uint2*)pembbf,
                                          (size_t)NP * DIM / 4);
    conv_kernel<<<640, 256, 0, stream>>>((const float4*)cemb, (uint2*)cembbf,
                                         (size_t)NC * DIM / 4);
    pack_kernel<<<40, 256, 0, stream>>>(w1p, w2p, w1c, w2c,
                                        w1pk_p, w2pk_p, w1pk_c, w2pk_c);

    bhist_kernel<<<256, 256, 0, stream>>>(ep, ec, PH, CH);
    bscan_kernel<<<1, 256, 0, stream>>>(PH, CH, POFF, COFF, PCUR, CCUR);

    int pblocks = (NE + CHUNK - 1) / CHUNK;   // 489
    part_kernel<<<pblocks, 256, 0, stream>>>(ep, ec, ew, PCUR, CCUR, Ap, Ac);

    bsort_kernel<1024, 15, 0x7FFFu><<<PBK, 256, 0, stream>>>(Ap, POFF, Sp, rowoff_p, NP, PBK);
    bsort_kernel<256, 17, 0x1FFFFu><<<CBK, 256, 0, stream>>>(Ac, COFF, Sc, rowoff_c, NC, CBK);

    agg_kernel<<<NP / 4, 256, 0, stream>>>(Sp, rowoff_p, cembbf, pmsgb);
    agg_kernel<<<NC / 4, 256, 0, stream>>>(Sc, rowoff_c, pembbf, cmsgb);

    float* out_p = (float*)d_out;             // [NP, 64]
    float* out_c = out_p + (size_t)NP * OUTD; // [NC, 64]

    mlp_mfma_kernel<<<(NP / 16 + 3) / 4, 256, 0, stream>>>(
        pembbf, pmsgb, w1pk_p, w2pk_p,
        b1p, g1p, be1p, b2p, g2p, be2p, out_p, NP);
    mlp_mfma_kernel<<<(NC / 16 + 3) / 4, 256, 0, stream>>>(
        cembbf, cmsgb, w1pk_c, w2pk_c,
        b1c, g1c, be1c, b2c, g2c, be2c, out_c, NC);
}

// Round 14
// 379.722 us; speedup vs baseline: 14.7165x; 1.0000x over previous
//
#include <hip/hip_runtime.h>
#include <cstddef>

#define NP 100000
#define NC 20000
#define NE 2000000
#define DIM 128
#define HID 128
#define OUTD 64

#define PBK 98      // ceil(NP/1024) buckets of 1024 providers
#define CBK 79      // ceil(NC/256)  buckets of 256 codes
#define CHUNK 4096  // edges per part-block

typedef __attribute__((ext_vector_type(8))) short short8v;
typedef __attribute__((ext_vector_type(4))) float f32x4;

__device__ __forceinline__ unsigned f2bf(float f) {
    unsigned u = __float_as_uint(f);
    return (u + 0x7FFFu + ((u >> 16) & 1u)) >> 16;   // RNE
}
__device__ __forceinline__ float bf2f(unsigned s) {
    return __uint_as_float(s << 16);
}

// ---------------- zero (bucket histograms only) ----------------
__global__ void zero4_kernel(float4* p, size_t n4) {
    size_t i = blockIdx.x * (size_t)blockDim.x + threadIdx.x;
    size_t stride = (size_t)gridDim.x * blockDim.x;
    float4 z = make_float4(0.f, 0.f, 0.f, 0.f);
    for (; i < n4; i += stride) p[i] = z;
}

// ---------------- f32 -> bf16 conversion ----------------
__global__ void conv_kernel(const float4* __restrict__ in, uint2* __restrict__ outp, size_t n4) {
    size_t i = blockIdx.x * (size_t)blockDim.x + threadIdx.x;
    size_t st = (size_t)gridDim.x * blockDim.x;
    for (; i < n4; i += st) {
        float4 v = in[i];
        outp[i] = make_uint2(f2bf(v.x) | (f2bf(v.y) << 16),
                             f2bf(v.z) | (f2bf(v.w) << 16));
    }
}

// ---------------- prepack weights into MFMA A-fragment order ----------------
__device__ __forceinline__ void pack_one(const float* __restrict__ w, unsigned short* __restrict__ dst,
                                         int M, int KT, int idx) {
    int lane = idx & 63;
    int rest = idx >> 6;
    int ks = rest % KT;
    int mt = rest / KT;
    int m  = mt * 16 + (lane & 15);
    int kb = ks * 32 + ((lane >> 4) << 3);
    uint4 r;
    r.x = f2bf(w[(kb + 0) * M + m]) | (f2bf(w[(kb + 1) * M + m]) << 16);
    r.y = f2bf(w[(kb + 2) * M + m]) | (f2bf(w[(kb + 3) * M + m]) << 16);
    r.z = f2bf(w[(kb + 4) * M + m]) | (f2bf(w[(kb + 5) * M + m]) << 16);
    r.w = f2bf(w[(kb + 6) * M + m]) | (f2bf(w[(kb + 7) * M + m]) << 16);
    *(uint4*)(dst + (size_t)idx * 8) = r;
}
__global__ __launch_bounds__(256) void pack_kernel(
    const float* __restrict__ w1p, const float* __restrict__ w2p,
    const float* __restrict__ w1c, const float* __restrict__ w2c,
    unsigned short* __restrict__ d1p, unsigned short* __restrict__ d2p,
    unsigned short* __restrict__ d1c, unsigned short* __restrict__ d2c) {
    int idx = blockIdx.x * 256 + threadIdx.x;     // 0..10239
    if (idx < 4096)       pack_one(w1p, d1p, 128, 8, idx);
    else if (idx < 5120)  pack_one(w2p, d2p, 64, 4, idx - 4096);
    else if (idx < 9216)  pack_one(w1c, d1c, 128, 8, idx - 5120);
    else if (idx < 10240) pack_one(w2c, d2c, 64, 4, idx - 9216);
}

// ---------------- bucket histogram ----------------
__global__ __launch_bounds__(256) void bhist_kernel(
    const int* __restrict__ ep, const int* __restrict__ ec,
    int* __restrict__ PH, int* __restrict__ CH)
{
    __shared__ int hp[PBK];
    __shared__ int hc[CBK];
    int t = threadIdx.x;
    if (t < PBK) hp[t] = 0;
    if (t < CBK) hc[t] = 0;
    __syncthreads();
    for (int e = blockIdx.x * 256 + t; e < NE; e += 256 * 256) {
        atomicAdd(&hp[ep[e] >> 10], 1);
        atomicAdd(&hc[ec[e] >> 8], 1);
    }
    __syncthreads();
    if (t < PBK) atomicAdd(&PH[t * 16], hp[t]);
    if (t < CBK) atomicAdd(&CH[t * 16], hc[t]);
}

// ---------------- bucket scans ----------------
__global__ __launch_bounds__(256) void bscan_kernel(
    const int* __restrict__ PH, const int* __restrict__ CH,
    int* __restrict__ POFF, int* __restrict__ COFF,
    int* __restrict__ PCUR, int* __restrict__ CCUR)
{
    __shared__ int s[256];
    int t = threadIdx.x;
    s[t] = (t < PBK) ? PH[t * 16] : 0;
    __syncthreads();
    for (int off = 1; off < 256; off <<= 1) {
        int a = (t >= off) ? s[t - off] : 0;
        __syncthreads();
        s[t] += a;
        __syncthreads();
    }
    int excl = t ? s[t - 1] : 0;
    if (t < PBK) { POFF[t] = excl; PCUR[t * 16] = excl; }
    if (t == 0) POFF[PBK] = NE;
    __syncthreads();
    s[t] = (t < CBK) ? CH[t * 16] : 0;
    __syncthreads();
    for (int off = 1; off < 256; off <<= 1) {
        int a = (t >= off) ? s[t - off] : 0;
        __syncthreads();
        s[t] += a;
        __syncthreads();
    }
    excl = t ? s[t - 1] : 0;
    if (t < CBK) { COFF[t] = excl; CCUR[t * 16] = excl; }
    if (t == 0) COFF[CBK] = NE;
}

// ---------------- pass A: partition into buckets ----------------
// P record: ((p&1023)<<15)|c ; C record: ((c&255)<<17)|p ; .y = weight bits
__global__ __launch_bounds__(256) void part_kernel(
    const int* __restrict__ ep, const int* __restrict__ ec, const float* __restrict__ ew,
    int* __restrict__ PCUR, int* __restrict__ CCUR,
    uint2* __restrict__ Ap, uint2* __restrict__ Ac)
{
    __shared__ int cp[PBK], bp_[PBK], cc[CBK], bc_[CBK];
    int t = threadIdx.x;
    int base = blockIdx.x * CHUNK;
    if (t < PBK) cp[t] = 0;
    if (t < CBK) cc[t] = 0;
    __syncthreads();
    #pragma unroll
    for (int i = 0; i < CHUNK / 256; ++i) {
        int e = base + i * 256 + t;
        if (e < NE) {
            atomicAdd(&cp[ep[e] >> 10], 1);
            atomicAdd(&cc[ec[e] >> 8], 1);
        }
    }
    __syncthreads();
    if (t < PBK) { bp_[t] = atomicAdd(&PCUR[t * 16], cp[t]); cp[t] = 0; }
    if (t < CBK) { bc_[t] = atomicAdd(&CCUR[t * 16], cc[t]); cc[t] = 0; }
    __syncthreads();
    #pragma unroll
    for (int i = 0; i < CHUNK / 256; ++i) {
        int e = base + i * 256 + t;
        if (e < NE) {
            unsigned p = (unsigned)ep[e];
            unsigned c = (unsigned)ec[e];
            unsigned wb = __float_as_uint(ew[e]);
            int b1 = p >> 10;
            int pos = bp_[b1] + atomicAdd(&cp[b1], 1);
            Ap[pos] = make_uint2(((p & 1023u) << 15) | c, wb);
            int b2 = c >> 8;
            int pos2 = bc_[b2] + atomicAdd(&cc[b2], 1);
            Ac[pos2] = make_uint2(((c & 255u) << 17) | p, wb);
        }
    }
}

// ---------------- pass B: within-bucket counting sort + per-row CSR ----------------
template<int LOCALS, int SHIFT, unsigned NMASK>
__global__ __launch_bounds__(256) void bsort_kernel(
    const uint2* __restrict__ A, const int* __restrict__ OFF,
    int2* __restrict__ S, int* __restrict__ rowoff, int nrows_total, int nbins)
{
    __shared__ int cnt[LOCALS];
    __shared__ int tsum[256];
    constexpr int NL = LOCALS / 256;
    int t = threadIdx.x;
    int b = blockIdx.x;
    int s0 = OFF[b], e0 = OFF[b + 1];
    #pragma unroll
    for (int k = 0; k < NL; ++k) cnt[t * NL + k] = 0;
    __syncthreads();
    for (int j = s0 + t; j < e0; j += 256)
        atomicAdd(&cnt[A[j].x >> SHIFT], 1);
    __syncthreads();
    int pre[NL];
    int run = 0;
    #pragma unroll
    for (int k = 0; k < NL; ++k) { pre[k] = run; run += cnt[t * NL + k]; }
    tsum[t] = run;
    __syncthreads();
    for (int off = 1; off < 256; off <<= 1) {
        int a = (t >= off) ? tsum[t - off] : 0;
        __syncthreads();
        tsum[t] += a;
        __syncthreads();
    }
    int excl = t ? tsum[t - 1] : 0;
    #pragma unroll
    for (int k = 0; k < NL; ++k) cnt[t * NL + k] = excl + pre[k];
    __syncthreads();
    int rowbase = b * LOCALS;
    #pragma unroll
    for (int k = 0; k < NL; ++k) {
        int r = t * NL + k;
        if (rowbase + r < nrows_total) rowoff[rowbase + r] = s0 + cnt[r];
    }
    if (b == nbins - 1 && t == 0) rowoff[nrows_total] = e0;
    __syncthreads();   // rowoff reads of cnt complete before scatter mutates cnt
    for (int j = s0 + t; j < e0; j += 256) {
        uint2 v = A[j];
        int loc = (int)(v.x >> SHIFT);
        int pos = s0 + atomicAdd(&cnt[loc], 1);
        S[pos] = make_int2((int)(v.x & NMASK), (int)v.y);
    }
}

// ---------------- aggregate: wave per row, bf16 gather, unroll x4 ----------------
// Fixed-point int32 accumulation (scale 2^21): integer sums are order-invariant,
// so the racy storage order upstream cannot change the output bit pattern
// between calls. Bounds: |emb| <= ~0.02, weighted degree <= ~300 ->
// |iacc| < 2^24, |ideg| < 2^30; per-term quantization 2^-21 (below bf16 LSB).
__global__ __launch_bounds__(256) void agg_kernel(
    const int2* __restrict__ sorted, const int* __restrict__ off,
    const unsigned short* __restrict__ nbremb_bf, unsigned short* __restrict__ msg_bf)
{
    const float SCL  = 2097152.0f;          // 2^21
    const float ISCL = 1.0f / 2097152.0f;
    int wave = threadIdx.x >> 6;
    int lane = threadIdx.x & 63;
    int row = blockIdx.x * 4 + wave;   // grid sized exactly
    int start = off[row];
    int end   = off[row + 1];
    int iacc0 = 0, iacc1 = 0, ideg = 0;
    int j = start;
    for (; j + 4 <= end; j += 4) {
        int2 v0 = sorted[j];
        int2 v1 = sorted[j + 1];
        int2 v2 = sorted[j + 2];
        int2 v3 = sorted[j + 3];
        unsigned pk0 = *(const unsigned*)(nbremb_bf + (size_t)v0.x * DIM + 2 * lane);
        unsigned pk1 = *(const unsigned*)(nbremb_bf + (size_t)v1.x * DIM + 2 * lane);
        unsigned pk2 = *(const unsigned*)(nbremb_bf + (size_t)v2.x * DIM + 2 * lane);
        unsigned pk3 = *(const unsigned*)(nbremb_bf + (size_t)v3.x * DIM + 2 * lane);
        float w0 = __int_as_float(v0.y), w1 = __int_as_float(v1.y);
        float w2 = __int_as_float(v2.y), w3 = __int_as_float(v3.y);
        ideg  += (int)(w0 * SCL) + (int)(w1 * SCL) + (int)(w2 * SCL) + (int)(w3 * SCL);
        iacc0 += (int)(w0 * bf2f(pk0 & 0xFFFFu) * SCL) + (int)(w1 * bf2f(pk1 & 0xFFFFu) * SCL)
               + (int)(w2 * bf2f(pk2 & 0xFFFFu) * SCL) + (int)(w3 * bf2f(pk3 & 0xFFFFu) * SCL);
        iacc1 += (int)(w0 * bf2f(pk0 >> 16) * SCL) + (int)(w1 * bf2f(pk1 >> 16) * SCL)
               + (int)(w2 * bf2f(pk2 >> 16) * SCL) + (int)(w3 * bf2f(pk3 >> 16) * SCL);
    }
    for (; j < end; ++j) {
        int2 v = sorted[j];
        float w = __int_as_float(v.y);
        unsigned pk = *(const unsigned*)(nbremb_bf + (size_t)v.x * DIM + 2 * lane);
        ideg  += (int)(w * SCL);
        iacc0 += (int)(w * bf2f(pk & 0xFFFFu) * SCL);
        iacc1 += (int)(w * bf2f(pk >> 16) * SCL);
    }
    float deg = (float)ideg * ISCL;
    float inv = 1.0f / (deg + 1e-8f);
    float a0 = (float)iacc0 * ISCL;
    float a1 = (float)iacc1 * ISCL;
    unsigned o = f2bf(a0 * inv) | (f2bf(a1 * inv) << 16);
    *(unsigned*)(msg_bf + (size_t)row * DIM + 2 * lane) = o;
}

// ---------------- MFMA MLP: swapped-operand, wave per 16 rows ----------------
#define HP 136   // hs row pitch in bf16
__global__ __launch_bounds__(256) void mlp_mfma_kernel(
    const unsigned short* __restrict__ embbf, const unsigned short* __restrict__ msgbf,
    const unsigned short* __restrict__ w1pk, const unsigned short* __restrict__ w2pk,
    const float* __restrict__ b1, const float* __restrict__ g1, const float* __restrict__ be1,
    const float* __restrict__ b2, const float* __restrict__ g2, const float* __restrict__ be2,
    float* __restrict__ out, int nrows)
{
    __shared__ __align__(16) unsigned short hs_all[4][16 * HP];
    int t = threadIdx.x;
    int wave = t >> 6, lane = t & 63;
    int tile = blockIdx.x * 4 + wave;
    if (tile * 16 >= nrows) return;          // padding waves only; no barriers used
    int r16 = lane & 15;
    int hi  = lane >> 4;
    int row = tile * 16 + r16;
    unsigned short* hs = hs_all[wave];

    // ---- layer 1: 8 mt x 8 ks MFMAs ----
    f32x4 acc[8];
    #pragma unroll
    for (int mt = 0; mt < 8; ++mt) {
        float4 bb = *(const float4*)&b1[mt * 16 + hi * 4];
        acc[mt] = (f32x4){bb.x, bb.y, bb.z, bb.w};
    }
    const unsigned short* x0 = embbf + (size_t)row * DIM;
    const unsigned short* x1 = msgbf + (size_t)row * DIM;
    #pragma unroll
    for (int ks = 0; ks < 8; ++ks) {
        const unsigned short* xs = (ks < 4) ? (x0 + ks * 32 + hi * 8)
                                            : (x1 + (ks - 4) * 32 + hi * 8);
        short8v bfrag = *(const short8v*)xs;
        #pragma unroll
        for (int mt = 0; mt < 8; ++mt) {
            short8v afrag = *(const short8v*)(w1pk + (((mt * 8 + ks) * 64 + lane) << 3));
            acc[mt] = __builtin_amdgcn_mfma_f32_16x16x32_bf16(afrag, bfrag, acc[mt], 0, 0, 0);
        }
    }

    // ---- LN1 + ReLU -> hs (bf16) ----
    float s = 0.f, q = 0.f;
    #pragma unroll
    for (int mt = 0; mt < 8; ++mt) {
        #pragma unroll
        for (int r = 0; r < 4; ++r) { float v = acc[mt][r]; s += v; q += v * v; }
    }
    s += __shfl_xor(s, 16); s += __shfl_xor(s, 32);
    q += __shfl_xor(q, 16); q += __shfl_xor(q, 32);
    float mu = s * (1.0f / 128.0f);
    float var = q * (1.0f / 128.0f) - mu * mu;
    float rstd = rsqrtf(var + 1e-5f);
    #pragma unroll
    for (int mt = 0; mt < 8; ++mt) {
        float4 gg = *(const float4*)&g1[mt * 16 + hi * 4];
        float4 bb = *(const float4*)&be1[mt * 16 + hi * 4];
        float h0 = fmaxf((acc[mt][0] - mu) * rstd * gg.x + bb.x, 0.f);
        float h1 = fmaxf((acc[mt][1] - mu) * rstd * gg.y + bb.y, 0.f);
        float h2 = fmaxf((acc[mt][2] - mu) * rstd * gg.z + bb.z, 0.f);
        float h3 = fmaxf((acc[mt][3] - mu) * rstd * gg.w + bb.w, 0.f);
        uint2 pk = make_uint2(f2bf(h0) | (f2bf(h1) << 16), f2bf(h2) | (f2bf(h3) << 16));
        *(uint2*)&hs[r16 * HP + mt * 16 + hi * 4] = pk;
    }

    // ---- layer 2: 4 mt x 4 ks MFMAs ----
    f32x4 acc2[4];
    #pragma unroll
    for (int mt = 0; mt < 4; ++mt) {
        float4 bb = *(const float4*)&b2[mt * 16 + hi * 4];
        acc2[mt] = (f32x4){bb.x, bb.y, bb.z, bb.w};
    }
    #pragma unroll
    for (int ks = 0; ks < 4; ++ks) {
        short8v bfrag = *(const short8v*)&hs[r16 * HP + ks * 32 + hi * 8];
        #pragma unroll
        for (int mt = 0; mt < 4; ++mt) {
            short8v afrag = *(const short8v*)(w2pk + (((mt * 4 + ks) * 64 + lane) << 3));
            acc2[mt] = __builtin_amdgcn_mfma_f32_16x16x32_bf16(afrag, bfrag, acc2[mt], 0, 0, 0);
        }
    }

    // ---- LN2 -> out ----
    float s2 = 0.f, q2 = 0.f;
    #pragma unroll
    for (int mt = 0; mt < 4; ++mt) {
        #pragma unroll
        for (int r = 0; r < 4; ++r) { float v = acc2[mt][r]; s2 += v; q2 += v * v; }
    }
    s2 += __shfl_xor(s2, 16); s2 += __shfl_xor(s2, 32);
    q2 += __shfl_xor(q2, 16); q2 += __shfl_xor(q2, 32);
    float mu2 = s2 * (1.0f / 64.0f);
    float var2 = q2 * (1.0f / 64.0f) - mu2 * mu2;
    float rstd2 = rsqrtf(var2 + 1e-5f);
    #pragma unroll
    for (int mt = 0; mt < 4; ++mt) {
        float4 gg = *(const float4*)&g2[mt * 16 + hi * 4];
        float4 bb = *(const float4*)&be2[mt * 16 + hi * 4];
        float4 o;
        o.x = (acc2[mt][0] - mu2) * rstd2 * gg.x + bb.x;
        o.y = (acc2[mt][1] - mu2) * rstd2 * gg.y + bb.y;
        o.z = (acc2[mt][2] - mu2) * rstd2 * gg.z + bb.z;
        o.w = (acc2[mt][3] - mu2) * rstd2 * gg.w + bb.w;
        *(float4*)&out[(size_t)row * OUTD + mt * 16 + hi * 4] = o;
    }
}

extern "C" void kernel_launch(void* const* d_in, const int* in_sizes, int n_in,
                              void* d_out, int out_size, void* d_ws, size_t ws_size,
                              hipStream_t stream) {
    const int*   ep   = (const int*)d_in[0];
    const int*   ec   = (const int*)d_in[1];
    const float* ew   = (const float*)d_in[2];
    const float* pemb = (const float*)d_in[3];
    const float* cemb = (const float*)d_in[4];
    const float* w1p  = (const float*)d_in[5];
    const float* b1p  = (const float*)d_in[6];
    const float* g1p  = (const float*)d_in[7];
    const float* be1p = (const float*)d_in[8];
    const float* w2p  = (const float*)d_in[9];
    const float* b2p  = (const float*)d_in[10];
    const float* g2p  = (const float*)d_in[11];
    const float* be2p = (const float*)d_in[12];
    const float* w1c  = (const float*)d_in[13];
    const float* b1c  = (const float*)d_in[14];
    const float* g1c  = (const float*)d_in[15];
    const float* be1c = (const float*)d_in[16];
    const float* w2c  = (const float*)d_in[17];
    const float* b2c  = (const float*)d_in[18];
    const float* g2c  = (const float*)d_in[19];
    const float* be2c = (const float*)d_in[20];

    // ---- meta workspace (ints) ----
    int* wsi  = (int*)d_ws;
    int* PH   = wsi;               // [98*16]  zeroed every call
    int* CH   = PH + 1568;         // [79*16]  zeroed every call
    int* PCUR = CH + 1264;         // [98*16]  (written by bscan)
    int* CCUR = PCUR + 1568;       // [79*16]
    int* POFF = CCUR + 1264;       // [100]
    int* COFF = POFF + 100;        // [84]
    int* rowoff_p = COFF + 84;         // [100004]
    int* rowoff_c = rowoff_p + 100004; // [20004]
    const int zero_ints = 1568 + 1264;                                      // 2832
    const int meta_ints = 2832 + 1568 + 1264 + 100 + 84 + 100004 + 20004;   // 125856

    // ---- big regions (stream-ordered lifetimes; aliases noted) ----
    char* big = (char*)(wsi + meta_ints);
    uint2* Ap = (uint2*)big;                             // 16 MB  (part out, bsort_p in)
    int2*  Sp = (int2*)(big + 16000000);                 // 16 MB  (bsort_p out, agg_p in)
    char*  zoneC = big + 32000000;                       // 30.72 MB zone
    uint2* Ac = (uint2*)zoneC;                           //   16 MB (part out, bsort_c in)
    int2*  Sc = (int2*)Ap;                               //   aliases Ap (dead after bsort_p)
    unsigned short* pmsgb = (unsigned short*)zoneC;                   // 25.6 MB (after bsort_c)
    unsigned short* cmsgb = (unsigned short*)(zoneC + 25600000);      // 5.12 MB
    unsigned short* pembbf = (unsigned short*)(zoneC + 30720000);     // 25.6 MB
    unsigned short* cembbf = pembbf + (size_t)NP * DIM;               // 5.12 MB
    unsigned short* w1pk_p = cembbf + (size_t)NC * DIM;  // 64 KB
    unsigned short* w2pk_p = w1pk_p + 32768;             // 16 KB
    unsigned short* w1pk_c = w2pk_p + 8192;              // 64 KB
    unsigned short* w2pk_c = w1pk_c + 32768;             // 16 KB

    zero4_kernel<<<3, 256, 0, stream>>>((float4*)wsi, (size_t)zero_ints / 4);

    // bf16 conversions + weight prepack (independent of edge pipeline)
    conv_kernel<<<2048, 256, 0, stream>>>((const float4*)pemb, (uint2*)pembbf,
                                          (size_t)NP * DIM / 4);
    conv_kernel<<<640, 256, 0, stream>>>((const float4*)cemb, (uint2*)cembbf,
                                         (size_t)NC * DIM / 4);
    pack_kernel<<<40, 256, 0, stream>>>(w1p, w2p, w1c, w2c,
                                        w1pk_p, w2pk_p, w1pk_c, w2pk_c);

    bhist_kernel<<<256, 256, 0, stream>>>(ep, ec, PH, CH);
    bscan_kernel<<<1, 256, 0, stream>>>(PH, CH, POFF, COFF, PCUR, CCUR);

    int pblocks = (NE + CHUNK - 1) / CHUNK;   // 489
    part_kernel<<<pblocks, 256, 0, stream>>>(ep, ec, ew, PCUR, CCUR, Ap, Ac);

    bsort_kernel<1024, 15, 0x7FFFu><<<PBK, 256, 0, stream>>>(Ap, POFF, Sp, rowoff_p, NP, PBK);
    bsort_kernel<256, 17, 0x1FFFFu><<<CBK, 256, 0, stream>>>(Ac, COFF, Sc, rowoff_c, NC, CBK);

    agg_kernel<<<NP / 4, 256, 0, stream>>>(Sp, rowoff_p, cembbf, pmsgb);
    agg_kernel<<<NC / 4, 256, 0, stream>>>(Sc, rowoff_c, pembbf, cmsgb);

    float* out_p = (float*)d_out;             // [NP, 64]
    float* out_c = out_p + (size_t)NP * OUTD; // [NC, 64]

    mlp_mfma_kernel<<<(NP / 16 + 3) / 4, 256, 0, stream>>>(
        pembbf, pmsgb, w1pk_p, w2pk_p,
        b1p, g1p, be1p, b2p, g2p, be2p, out_p, NP);
    mlp_mfma_kernel<<<(NC / 16 + 3) / 4, 256, 0, stream>>>(
        cembbf, cmsgb, w1pk_c, w2pk_c,
        b1c, g1c, be1c, b2c, g2c, be2c, out_c, NC);
}